// Round 1
// baseline (378.544 us; speedup 1.0000x reference)
//
#include <hip/hip_runtime.h>

#define HH 128
#define WW 128
#define CC 64
#define OCC 64
#define BB 8

// ws layout (bytes)
#define W1T_OFF 0          // [c][t][27] floats = 15552 (62208 B)
#define W2T_OFF 65536      // [k][c][64] floats = 36864 (147456 B)
#define WS_NEED (65536 + 147456)

__global__ void transpose_weights(const float* __restrict__ weight,
                                  const float* __restrict__ offset_w,
                                  const float* __restrict__ mask_w,
                                  float* __restrict__ ws) {
    int tid = blockIdx.x * 256 + threadIdx.x;
    if (tid < 15552) {
        // W1T[tid], tid = c*243 + t*27 + j
        int j = tid % 27;
        int t = (tid / 27) % 9;
        int c = tid / 243;
        float v;
        if (j < 18) v = offset_w[(j * CC + c) * 9 + t];
        else        v = mask_w[((j - 18) * CC + c) * 9 + t];
        ws[tid] = v;
    } else {
        int u = tid - 15552;
        if (u < 36864) {
            // W2T[u], u = k*4096 + c*64 + oc
            int oc = u & 63;
            int c = (u >> 6) & 63;
            int k = u >> 12;
            ((float*)((char*)ws + W2T_OFF))[u] = weight[(oc * CC + c) * 9 + k];
        }
    }
}

template <bool TRANS>
__global__ __launch_bounds__(256)
void deform_fused(const float* __restrict__ x,
                  const float* __restrict__ weight,
                  const float* __restrict__ bias,
                  const float* __restrict__ offset_w,
                  const float* __restrict__ offset_b,
                  const float* __restrict__ mask_w,
                  const float* __restrict__ mask_b,
                  const float* __restrict__ ws,
                  float* __restrict__ out) {
    int p = blockIdx.x * 256 + threadIdx.x;
    int ow = p & (WW - 1);
    int oh = (p >> 7) & (HH - 1);
    int b = p >> 14;

    const float* xb = x + (size_t)b * CC * HH * WW;

    // ---- Phase A: 3x3 conv producing 18 offset + 9 mask channels at (oh,ow)
    float acc[27];
#pragma unroll
    for (int j = 0; j < 18; j++) acc[j] = offset_b[j];
#pragma unroll
    for (int j = 0; j < 9; j++) acc[18 + j] = mask_b[j];

    for (int c = 0; c < CC; c++) {
        const float* xc = xb + c * HH * WW;
        float xv[9];
#pragma unroll
        for (int t = 0; t < 9; t++) {
            int iy = oh - 1 + t / 3;
            int ix = ow - 1 + t % 3;
            bool v = (iy >= 0) && (iy < HH) && (ix >= 0) && (ix < WW);
            xv[t] = v ? xc[iy * WW + ix] : 0.f;
        }
        if (TRANS) {
            const float* w1 = ws + (size_t)c * 243;
#pragma unroll
            for (int t = 0; t < 9; t++) {
#pragma unroll
                for (int j = 0; j < 27; j++)
                    acc[j] += xv[t] * w1[t * 27 + j];
            }
        } else {
#pragma unroll
            for (int t = 0; t < 9; t++) {
#pragma unroll
                for (int j = 0; j < 27; j++) {
                    float wv = (j < 18) ? offset_w[(j * CC + c) * 9 + t]
                                        : mask_w[((j - 18) * CC + c) * 9 + t];
                    acc[j] += xv[t] * wv;
                }
            }
        }
    }

    // ---- Phase B: deformable sampling + einsum over (c,k) into 64 oc accumulators
    float acc2[OCC];
#pragma unroll
    for (int o = 0; o < OCC; o++) acc2[o] = 0.f;

    const float* w2 = (const float*)((const char*)ws + W2T_OFF);

#pragma unroll
    for (int k = 0; k < 9; k++) {
        float dy = acc[2 * k];
        float dx = acc[2 * k + 1];
        float m = 1.f / (1.f + __expf(-acc[18 + k]));

        float py = (float)(oh - 1 + k / 3) + dy;
        float px = (float)(ow - 1 + k % 3) + dx;
        float y0f = floorf(py), x0f = floorf(px);
        float fy = py - y0f, fx = px - x0f;
        int y0 = (int)y0f, x0 = (int)x0f;
        int y1 = y0 + 1, x1 = x0 + 1;
        bool vy0 = (y0 >= 0) && (y0 < HH);
        bool vy1 = (y1 >= 0) && (y1 < HH);
        bool vx0 = (x0 >= 0) && (x0 < WW);
        bool vx1 = (x1 >= 0) && (x1 < WW);
        float w00 = (vy0 && vx0) ? (1.f - fy) * (1.f - fx) * m : 0.f;
        float w01 = (vy0 && vx1) ? (1.f - fy) * fx * m : 0.f;
        float w10 = (vy1 && vx0) ? fy * (1.f - fx) * m : 0.f;
        float w11 = (vy1 && vx1) ? fy * fx * m : 0.f;
        int iy0 = min(max(y0, 0), HH - 1), iy1 = min(max(y1, 0), HH - 1);
        int ix0 = min(max(x0, 0), WW - 1), ix1 = min(max(x1, 0), WW - 1);
        int o00 = iy0 * WW + ix0, o01 = iy0 * WW + ix1;
        int o10 = iy1 * WW + ix0, o11 = iy1 * WW + ix1;

        for (int c = 0; c < CC; c++) {
            const float* xc = xb + c * HH * WW;
            float v = w00 * xc[o00] + w01 * xc[o01] + w10 * xc[o10] + w11 * xc[o11];
            if (TRANS) {
                const float* wr = w2 + ((size_t)k * CC + c) * OCC;
#pragma unroll
                for (int o = 0; o < OCC; o++) acc2[o] += v * wr[o];
            } else {
#pragma unroll
                for (int o = 0; o < OCC; o++) acc2[o] += v * weight[(o * CC + c) * 9 + k];
            }
        }
    }

    float* ob = out + (size_t)b * OCC * HH * WW + oh * WW + ow;
#pragma unroll
    for (int o = 0; o < OCC; o++) ob[(size_t)o * HH * WW] = acc2[o] + bias[o];
}

extern "C" void kernel_launch(void* const* d_in, const int* in_sizes, int n_in,
                              void* d_out, int out_size, void* d_ws, size_t ws_size,
                              hipStream_t stream) {
    const float* x        = (const float*)d_in[0];
    const float* weight   = (const float*)d_in[1];
    const float* bias     = (const float*)d_in[2];
    const float* offset_w = (const float*)d_in[3];
    const float* offset_b = (const float*)d_in[4];
    const float* mask_w   = (const float*)d_in[5];
    const float* mask_b   = (const float*)d_in[6];
    float* out = (float*)d_out;

    const int npix = BB * HH * WW;          // 131072
    const int blocks = npix / 256;          // 512

    if (ws_size >= (size_t)WS_NEED) {
        transpose_weights<<<205, 256, 0, stream>>>(weight, offset_w, mask_w, (float*)d_ws);
        deform_fused<true><<<blocks, 256, 0, stream>>>(x, weight, bias, offset_w, offset_b,
                                                       mask_w, mask_b, (const float*)d_ws, out);
    } else {
        deform_fused<false><<<blocks, 256, 0, stream>>>(x, weight, bias, offset_w, offset_b,
                                                        mask_w, mask_b, nullptr, out);
    }
}

// Round 2
// 285.039 us; speedup vs baseline: 1.3280x; 1.3280x over previous
//
#include <hip/hip_runtime.h>

#define HH 128
#define WW 128
#define CC 64
#define OCC 64
#define BB 8
#define NPIX (BB * HH * WW)   // 131072
#define KQ 576                // 9 * 64, q = k*64 + c

typedef __attribute__((ext_vector_type(4))) float f32x4;
typedef __attribute__((ext_vector_type(8))) short bf16x8;

// ws layout (bytes)
#define CO_OFF 0                        // co  [NPIX][32] f32   = 16,777,216 B
#define W1_OFF 16777216                 // W1  [32][576] bf16   = 36,864 B
#define W2_OFF 16814080                 // W2  [64][576] bf16   = 73,728 B
#define WS_NEED (16814080 + 73728)

__device__ __forceinline__ short f2bf(float f) {
    union { float f; unsigned u; } v; v.f = f;
    unsigned r = v.u + 0x7FFF + ((v.u >> 16) & 1);   // RNE
    return (short)(r >> 16);
}

// ---------------- K0: pack weights to bf16, q = k*64 + c ----------------
__global__ void prep_weights(const float* __restrict__ weight,
                             const float* __restrict__ offset_w,
                             const float* __restrict__ mask_w,
                             short* __restrict__ w1, short* __restrict__ w2) {
    int tid = blockIdx.x * 256 + threadIdx.x;
    if (tid < 32 * KQ) {
        int q = tid % KQ, r = tid / KQ;
        int k = q >> 6, c = q & 63;
        float v = 0.f;
        if (r < 18)      v = offset_w[(r * CC + c) * 9 + k];
        else if (r < 27) v = mask_w[((r - 18) * CC + c) * 9 + k];
        w1[tid] = f2bf(v);
    } else {
        int u = tid - 32 * KQ;
        if (u < 64 * KQ) {
            int q = u % KQ, oc = u / KQ;
            int k = q >> 6, c = q & 63;
            w2[u] = f2bf(weight[(oc * CC + c) * 9 + k]);
        }
    }
}

// ---------------- K1: offset/mask conv via MFMA -> co[p][32] ----------------
// D[ochan][pixel]: A = W1[ochan][q], B[q][pixel] = x-tap, built in registers.
__global__ __launch_bounds__(256) void conv_mfma(
    const float* __restrict__ x,
    const float* __restrict__ offset_b,
    const float* __restrict__ mask_b,
    const short* __restrict__ w1,
    float* __restrict__ co) {
    int lane = threadIdx.x & 63;
    int wv = threadIdx.x >> 6;
    int p0 = blockIdx.x * 64 + wv * 16;
    int col = lane & 15;         // pixel within tile (B col / D col)
    int qg = lane >> 4;          // K sub-group
    int p = p0 + col;
    int ow = p & (WW - 1);
    int oh = (p >> 7) & (HH - 1);
    int b = p >> 14;
    const float* xb = x + (size_t)b * CC * HH * WW;

    f32x4 acc0 = {0.f, 0.f, 0.f, 0.f}, acc1 = {0.f, 0.f, 0.f, 0.f};

#pragma unroll 2
    for (int ch = 0; ch < 18; ch++) {
        int k = ch >> 1;
        int c0 = ((ch & 1) << 5) + (qg << 3);
        int iy = oh - 1 + k / 3;
        int ix = ow - 1 + (k - (k / 3) * 3);
        bool vv = (iy >= 0) && (iy < HH) && (ix >= 0) && (ix < WW);
        int base = iy * WW + ix;
        bf16x8 bfr;
#pragma unroll
        for (int i = 0; i < 8; i++) {
            float v = 0.f;
            if (vv) v = xb[(size_t)(c0 + i) * HH * WW + base];
            bfr[i] = f2bf(v);
        }
        const short* ap = w1 + (size_t)col * KQ + ch * 32 + (qg << 3);
        bf16x8 a0 = *(const bf16x8*)ap;
        bf16x8 a1 = *(const bf16x8*)(ap + 16 * KQ);
        acc0 = __builtin_amdgcn_mfma_f32_16x16x32_bf16(a0, bfr, acc0, 0, 0, 0);
        acc1 = __builtin_amdgcn_mfma_f32_16x16x32_bf16(a1, bfr, acc1, 0, 0, 0);
    }

    // D: col = pixel (lane&15), row = qg*4 + j.  co[p][32] with dwordx4 stores.
    float* cop = co + (size_t)p * 32;
    f32x4 s0, s1;
#pragma unroll
    for (int j = 0; j < 4; j++) {
        int r0 = (qg << 2) + j;        // 0..15  -> offset_b
        int r1 = 16 + r0;              // 16..31 -> offset_b/mask_b/pad
        float b1 = (r1 < 18) ? offset_b[r1] : (r1 < 27 ? mask_b[r1 - 18] : 0.f);
        s0[j] = acc0[j] + offset_b[r0];
        s1[j] = acc1[j] + b1;
    }
    *(f32x4*)(cop + (qg << 2)) = s0;
    *(f32x4*)(cop + 16 + (qg << 2)) = s1;
}

// ---------------- K2: deformable gather + einsum via MFMA ----------------
// D[oc][pixel]: A = W2[oc][q], B[q][pixel] = bilinear sample (mask folded).
__global__ __launch_bounds__(256) void deform_mfma(
    const float* __restrict__ x,
    const float* __restrict__ bias,
    const short* __restrict__ w2,
    const float* __restrict__ co,
    float* __restrict__ out) {
    int lane = threadIdx.x & 63;
    int wv = threadIdx.x >> 6;
    int p0 = blockIdx.x * 64 + wv * 16;
    int col = lane & 15;
    int qg = lane >> 4;
    int p = p0 + col;
    int ow = p & (WW - 1);
    int oh = (p >> 7) & (HH - 1);
    int b = p >> 14;
    const float* xb = x + (size_t)b * CC * HH * WW;

    f32x4 acc0 = {0.f,0.f,0.f,0.f}, acc1 = {0.f,0.f,0.f,0.f};
    f32x4 acc2 = {0.f,0.f,0.f,0.f}, acc3 = {0.f,0.f,0.f,0.f};

    float w00 = 0.f, w01 = 0.f, w10 = 0.f, w11 = 0.f;
    int o00 = 0, o01 = 0, o10 = 0, o11 = 0;

#pragma unroll 2
    for (int ch = 0; ch < 18; ch++) {
        if ((ch & 1) == 0) {
            int k = ch >> 1;
            float dy = co[(size_t)p * 32 + 2 * k];
            float dx = co[(size_t)p * 32 + 2 * k + 1];
            float mr = co[(size_t)p * 32 + 18 + k];
            float m = 1.f / (1.f + __expf(-mr));
            float py = (float)(oh - 1 + k / 3) + dy;
            float px = (float)(ow - 1 + (k - (k / 3) * 3)) + dx;
            float y0f = floorf(py), x0f = floorf(px);
            float fy = py - y0f, fx = px - x0f;
            int y0 = (int)y0f, xq = (int)x0f;
            int y1 = y0 + 1, x1 = xq + 1;
            bool vy0 = (y0 >= 0) && (y0 < HH), vy1 = (y1 >= 0) && (y1 < HH);
            bool vx0 = (xq >= 0) && (xq < WW), vx1 = (x1 >= 0) && (x1 < WW);
            w00 = (vy0 && vx0) ? (1.f - fy) * (1.f - fx) * m : 0.f;
            w01 = (vy0 && vx1) ? (1.f - fy) * fx * m : 0.f;
            w10 = (vy1 && vx0) ? fy * (1.f - fx) * m : 0.f;
            w11 = (vy1 && vx1) ? fy * fx * m : 0.f;
            int iy0 = min(max(y0, 0), HH - 1), iy1 = min(max(y1, 0), HH - 1);
            int ix0 = min(max(xq, 0), WW - 1), ix1 = min(max(x1, 0), WW - 1);
            o00 = iy0 * WW + ix0; o01 = iy0 * WW + ix1;
            o10 = iy1 * WW + ix0; o11 = iy1 * WW + ix1;
        }
        int c0 = ((ch & 1) << 5) + (qg << 3);
        bf16x8 bfr;
#pragma unroll
        for (int i = 0; i < 8; i++) {
            const float* xc = xb + (size_t)(c0 + i) * HH * WW;
            float v = w00 * xc[o00] + w01 * xc[o01] + w10 * xc[o10] + w11 * xc[o11];
            bfr[i] = f2bf(v);
        }
        const short* ap = w2 + (size_t)col * KQ + ch * 32 + (qg << 3);
        bf16x8 a0 = *(const bf16x8*)ap;
        bf16x8 a1 = *(const bf16x8*)(ap + 16 * KQ);
        bf16x8 a2 = *(const bf16x8*)(ap + 32 * KQ);
        bf16x8 a3 = *(const bf16x8*)(ap + 48 * KQ);
        acc0 = __builtin_amdgcn_mfma_f32_16x16x32_bf16(a0, bfr, acc0, 0, 0, 0);
        acc1 = __builtin_amdgcn_mfma_f32_16x16x32_bf16(a1, bfr, acc1, 0, 0, 0);
        acc2 = __builtin_amdgcn_mfma_f32_16x16x32_bf16(a2, bfr, acc2, 0, 0, 0);
        acc3 = __builtin_amdgcn_mfma_f32_16x16x32_bf16(a3, bfr, acc3, 0, 0, 0);
    }

    // D: col = pixel, row = oc_tile*16 + qg*4 + j
    size_t ob = (size_t)b * OCC * HH * WW + (size_t)oh * WW + ow;
#pragma unroll
    for (int j = 0; j < 4; j++) {
        int r = (qg << 2) + j;
        out[ob + (size_t)r * HH * WW]        = acc0[j] + bias[r];
        out[ob + (size_t)(r + 16) * HH * WW] = acc1[j] + bias[r + 16];
        out[ob + (size_t)(r + 32) * HH * WW] = acc2[j] + bias[r + 32];
        out[ob + (size_t)(r + 48) * HH * WW] = acc3[j] + bias[r + 48];
    }
}

// ---------------- Fallback (validated round-1 structure, all-f32) ----------------
__global__ __launch_bounds__(256)
void deform_fused_fb(const float* __restrict__ x,
                     const float* __restrict__ weight,
                     const float* __restrict__ bias,
                     const float* __restrict__ offset_w,
                     const float* __restrict__ offset_b,
                     const float* __restrict__ mask_w,
                     const float* __restrict__ mask_b,
                     float* __restrict__ out) {
    int p = blockIdx.x * 256 + threadIdx.x;
    int ow = p & (WW - 1);
    int oh = (p >> 7) & (HH - 1);
    int b = p >> 14;
    const float* xb = x + (size_t)b * CC * HH * WW;

    float acc[27];
#pragma unroll
    for (int j = 0; j < 18; j++) acc[j] = offset_b[j];
#pragma unroll
    for (int j = 0; j < 9; j++) acc[18 + j] = mask_b[j];

    for (int c = 0; c < CC; c++) {
        const float* xc = xb + c * HH * WW;
        float xv[9];
#pragma unroll
        for (int t = 0; t < 9; t++) {
            int iy = oh - 1 + t / 3;
            int ix = ow - 1 + t % 3;
            bool v = (iy >= 0) && (iy < HH) && (ix >= 0) && (ix < WW);
            xv[t] = v ? xc[iy * WW + ix] : 0.f;
        }
#pragma unroll
        for (int t = 0; t < 9; t++)
#pragma unroll
            for (int j = 0; j < 27; j++) {
                float wv = (j < 18) ? offset_w[(j * CC + c) * 9 + t]
                                    : mask_w[((j - 18) * CC + c) * 9 + t];
                acc[j] += xv[t] * wv;
            }
    }

    float acc2[OCC];
#pragma unroll
    for (int o = 0; o < OCC; o++) acc2[o] = 0.f;

#pragma unroll
    for (int k = 0; k < 9; k++) {
        float dy = acc[2 * k], dx = acc[2 * k + 1];
        float m = 1.f / (1.f + __expf(-acc[18 + k]));
        float py = (float)(oh - 1 + k / 3) + dy;
        float px = (float)(ow - 1 + k % 3) + dx;
        float y0f = floorf(py), x0f = floorf(px);
        float fy = py - y0f, fx = px - x0f;
        int y0 = (int)y0f, x0 = (int)x0f;
        int y1 = y0 + 1, x1 = x0 + 1;
        bool vy0 = (y0 >= 0) && (y0 < HH), vy1 = (y1 >= 0) && (y1 < HH);
        bool vx0 = (x0 >= 0) && (x0 < WW), vx1 = (x1 >= 0) && (x1 < WW);
        float w00 = (vy0 && vx0) ? (1.f - fy) * (1.f - fx) * m : 0.f;
        float w01 = (vy0 && vx1) ? (1.f - fy) * fx * m : 0.f;
        float w10 = (vy1 && vx0) ? fy * (1.f - fx) * m : 0.f;
        float w11 = (vy1 && vx1) ? fy * fx * m : 0.f;
        int iy0 = min(max(y0, 0), HH - 1), iy1 = min(max(y1, 0), HH - 1);
        int ix0 = min(max(x0, 0), WW - 1), ix1 = min(max(x1, 0), WW - 1);
        int o00 = iy0 * WW + ix0, o01 = iy0 * WW + ix1;
        int o10 = iy1 * WW + ix0, o11 = iy1 * WW + ix1;
        for (int c = 0; c < CC; c++) {
            const float* xc = xb + c * HH * WW;
            float v = w00 * xc[o00] + w01 * xc[o01] + w10 * xc[o10] + w11 * xc[o11];
#pragma unroll
            for (int o = 0; o < OCC; o++) acc2[o] += v * weight[(o * CC + c) * 9 + k];
        }
    }
    float* ob = out + (size_t)b * OCC * HH * WW + oh * WW + ow;
#pragma unroll
    for (int o = 0; o < OCC; o++) ob[(size_t)o * HH * WW] = acc2[o] + bias[o];
}

extern "C" void kernel_launch(void* const* d_in, const int* in_sizes, int n_in,
                              void* d_out, int out_size, void* d_ws, size_t ws_size,
                              hipStream_t stream) {
    const float* x        = (const float*)d_in[0];
    const float* weight   = (const float*)d_in[1];
    const float* bias     = (const float*)d_in[2];
    const float* offset_w = (const float*)d_in[3];
    const float* offset_b = (const float*)d_in[4];
    const float* mask_w   = (const float*)d_in[5];
    const float* mask_b   = (const float*)d_in[6];
    float* out = (float*)d_out;

    if (ws_size >= (size_t)WS_NEED) {
        float* co = (float*)((char*)d_ws + CO_OFF);
        short* w1 = (short*)((char*)d_ws + W1_OFF);
        short* w2 = (short*)((char*)d_ws + W2_OFF);
        prep_weights<<<216, 256, 0, stream>>>(weight, offset_w, mask_w, w1, w2);
        conv_mfma<<<NPIX / 64, 256, 0, stream>>>(x, offset_b, mask_b, w1, co);
        deform_mfma<<<NPIX / 64, 256, 0, stream>>>(x, bias, w2, co, out);
    } else {
        deform_fused_fb<<<NPIX / 256, 256, 0, stream>>>(x, weight, bias, offset_w, offset_b,
                                                        mask_w, mask_b, out);
    }
}

// Round 3
// 281.519 us; speedup vs baseline: 1.3446x; 1.0125x over previous
//
#include <hip/hip_runtime.h>

#define HH 128
#define WW 128
#define CC 64
#define OCC 64
#define BB 8
#define NPIX (BB * HH * WW)   // 131072
#define KQ 576                // 9 * 64, q = k*64 + c

typedef __attribute__((ext_vector_type(4))) float f32x4;
typedef __attribute__((ext_vector_type(8))) short bf16x8;

// ---- ws layout, full (NHWC) path ----
#define XT_OFF 0                         // xt [B][H][W][C] f32 = 33,554,432 B
#define CO_OFF 33554432                  // co [NPIX][32] f32   = 16,777,216 B
#define W1_OFF 50331648                  // W1 [32][576] bf16   = 36,864 B
#define W2_OFF 50368512                  // W2 [64][576] bf16   = 73,728 B
#define WS_FULL (50368512 + 73728)
// ---- ws layout, mid (NCHW) path ----
#define CO2_OFF 0
#define W1B_OFF 16777216
#define W2B_OFF 16814080
#define WS_MID (16814080 + 73728)

__device__ __forceinline__ short f2bf(float f) {
    union { float f; unsigned u; } v; v.f = f;
    unsigned r = v.u + 0x7FFF + ((v.u >> 16) & 1);   // RNE
    return (short)(r >> 16);
}

// ---------------- K0: pack weights to bf16, q = k*64 + c ----------------
__global__ void prep_weights(const float* __restrict__ weight,
                             const float* __restrict__ offset_w,
                             const float* __restrict__ mask_w,
                             short* __restrict__ w1, short* __restrict__ w2) {
    int tid = blockIdx.x * 256 + threadIdx.x;
    if (tid < 32 * KQ) {
        int q = tid % KQ, r = tid / KQ;
        int k = q >> 6, c = q & 63;
        float v = 0.f;
        if (r < 18)      v = offset_w[(r * CC + c) * 9 + k];
        else if (r < 27) v = mask_w[((r - 18) * CC + c) * 9 + k];
        w1[tid] = f2bf(v);
    } else {
        int u = tid - 32 * KQ;
        if (u < 64 * KQ) {
            int q = u % KQ, oc = u / KQ;
            int k = q >> 6, c = q & 63;
            w2[u] = f2bf(weight[(oc * CC + c) * 9 + k]);
        }
    }
}

// ---------------- K0b: NCHW -> NHWC transpose of x ----------------
// One block per (b,h) row: 64 c x 128 w = 32 KB through LDS.
__global__ __launch_bounds__(256) void transpose_x(
    const float* __restrict__ x, float* __restrict__ xt) {
    __shared__ float lds[128 * 65];
    int bh = blockIdx.x;           // b*128 + h
    int b = bh >> 7, h = bh & 127;
    const float* xr = x + ((size_t)b * CC * HH + h) * WW;   // + c*HH*WW + w
    int tid = threadIdx.x;
#pragma unroll
    for (int it = 0; it < 32; it++) {
        int e = it * 256 + tid;
        int c = e >> 7, w = e & 127;
        lds[w * 65 + c] = xr[(size_t)c * HH * WW + w];
    }
    __syncthreads();
    float* otr = xt + (size_t)bh * WW * CC;   // + w*64 + c
#pragma unroll
    for (int it = 0; it < 32; it++) {
        int e = it * 256 + tid;
        int w = e >> 6, c = e & 63;
        otr[e] = lds[w * 65 + c];
    }
}

// ---------------- K1: offset/mask conv via MFMA -> co[p][32] ----------------
template <bool NHWC>
__global__ __launch_bounds__(256) void conv_mfma(
    const float* __restrict__ xin,       // NHWC ? xt : x
    const float* __restrict__ offset_b,
    const float* __restrict__ mask_b,
    const short* __restrict__ w1,
    float* __restrict__ co) {
    int lane = threadIdx.x & 63;
    int wv = threadIdx.x >> 6;
    int p0 = blockIdx.x * 64 + wv * 16;
    int col = lane & 15;         // pixel within tile
    int qg = lane >> 4;          // K sub-group
    int p = p0 + col;
    int ow = p & (WW - 1);
    int oh = (p >> 7) & (HH - 1);
    int b = p >> 14;
    const float* xb = xin + (size_t)b * CC * HH * WW;

    f32x4 acc0 = {0.f, 0.f, 0.f, 0.f}, acc1 = {0.f, 0.f, 0.f, 0.f};

#pragma unroll 2
    for (int ch = 0; ch < 18; ch++) {
        int k = ch >> 1;
        int c0 = ((ch & 1) << 5) + (qg << 3);
        int iy = oh - 1 + k / 3;
        int ix = ow - 1 + (k - (k / 3) * 3);
        bool vv = (iy >= 0) && (iy < HH) && (ix >= 0) && (ix < WW);
        bf16x8 bfr;
        if (NHWC) {
            f32x4 va = {0.f,0.f,0.f,0.f}, vb = {0.f,0.f,0.f,0.f};
            if (vv) {
                const float* tp = xb + (size_t)(iy * WW + ix) * CC + c0;
                va = *(const f32x4*)tp;
                vb = *(const f32x4*)(tp + 4);
            }
#pragma unroll
            for (int i = 0; i < 4; i++) { bfr[i] = f2bf(va[i]); bfr[4 + i] = f2bf(vb[i]); }
        } else {
            int base = iy * WW + ix;
#pragma unroll
            for (int i = 0; i < 8; i++) {
                float v = 0.f;
                if (vv) v = xb[(size_t)(c0 + i) * HH * WW + base];
                bfr[i] = f2bf(v);
            }
        }
        const short* ap = w1 + (size_t)col * KQ + ch * 32 + (qg << 3);
        bf16x8 a0 = *(const bf16x8*)ap;
        bf16x8 a1 = *(const bf16x8*)(ap + 16 * KQ);
        acc0 = __builtin_amdgcn_mfma_f32_16x16x32_bf16(a0, bfr, acc0, 0, 0, 0);
        acc1 = __builtin_amdgcn_mfma_f32_16x16x32_bf16(a1, bfr, acc1, 0, 0, 0);
    }

    float* cop = co + (size_t)p * 32;
    f32x4 s0, s1;
#pragma unroll
    for (int j = 0; j < 4; j++) {
        int r0 = (qg << 2) + j;
        int r1 = 16 + r0;
        float b1 = (r1 < 18) ? offset_b[r1] : (r1 < 27 ? mask_b[r1 - 18] : 0.f);
        s0[j] = acc0[j] + offset_b[r0];
        s1[j] = acc1[j] + b1;
    }
    *(f32x4*)(cop + (qg << 2)) = s0;
    *(f32x4*)(cop + 16 + (qg << 2)) = s1;
}

// ---------------- K2: deformable gather + einsum via MFMA ----------------
template <bool NHWC>
__global__ __launch_bounds__(256) void deform_mfma(
    const float* __restrict__ xin,       // NHWC ? xt : x
    const float* __restrict__ bias,
    const short* __restrict__ w2,
    const float* __restrict__ co,
    float* __restrict__ out) {
    int lane = threadIdx.x & 63;
    int wv = threadIdx.x >> 6;
    int p0 = blockIdx.x * 64 + wv * 16;
    int col = lane & 15;
    int qg = lane >> 4;
    int p = p0 + col;
    int ow = p & (WW - 1);
    int oh = (p >> 7) & (HH - 1);
    int b = p >> 14;
    const float* xb = xin + (size_t)b * CC * HH * WW;
    const float* cop = co + (size_t)p * 32;

    f32x4 acc0 = {0.f,0.f,0.f,0.f}, acc1 = {0.f,0.f,0.f,0.f};
    f32x4 acc2 = {0.f,0.f,0.f,0.f}, acc3 = {0.f,0.f,0.f,0.f};

    float w00 = 0.f, w01 = 0.f, w10 = 0.f, w11 = 0.f;
    int o00 = 0, o01 = 0, o10 = 0, o11 = 0;

#pragma unroll 2
    for (int ch = 0; ch < 18; ch++) {
        if ((ch & 1) == 0) {
            int k = ch >> 1;
            float dy = cop[2 * k];
            float dx = cop[2 * k + 1];
            float mr = cop[18 + k];
            float m = 1.f / (1.f + __expf(-mr));
            float py = (float)(oh - 1 + k / 3) + dy;
            float px = (float)(ow - 1 + (k - (k / 3) * 3)) + dx;
            float y0f = floorf(py), x0f = floorf(px);
            float fy = py - y0f, fx = px - x0f;
            int y0 = (int)y0f, xq = (int)x0f;
            int y1 = y0 + 1, x1 = xq + 1;
            bool vy0 = (y0 >= 0) && (y0 < HH), vy1 = (y1 >= 0) && (y1 < HH);
            bool vx0 = (xq >= 0) && (xq < WW), vx1 = (x1 >= 0) && (x1 < WW);
            w00 = (vy0 && vx0) ? (1.f - fy) * (1.f - fx) * m : 0.f;
            w01 = (vy0 && vx1) ? (1.f - fy) * fx * m : 0.f;
            w10 = (vy1 && vx0) ? fy * (1.f - fx) * m : 0.f;
            w11 = (vy1 && vx1) ? fy * fx * m : 0.f;
            int iy0 = min(max(y0, 0), HH - 1), iy1 = min(max(y1, 0), HH - 1);
            int ix0 = min(max(xq, 0), WW - 1), ix1 = min(max(x1, 0), WW - 1);
            o00 = iy0 * WW + ix0; o01 = iy0 * WW + ix1;
            o10 = iy1 * WW + ix0; o11 = iy1 * WW + ix1;
        }
        int c0 = ((ch & 1) << 5) + (qg << 3);
        bf16x8 bfr;
        if (NHWC) {
            const float* t00 = xb + (size_t)o00 * CC + c0;
            const float* t01 = xb + (size_t)o01 * CC + c0;
            const float* t10 = xb + (size_t)o10 * CC + c0;
            const float* t11 = xb + (size_t)o11 * CC + c0;
            f32x4 a00 = *(const f32x4*)t00, b00 = *(const f32x4*)(t00 + 4);
            f32x4 a01 = *(const f32x4*)t01, b01 = *(const f32x4*)(t01 + 4);
            f32x4 a10 = *(const f32x4*)t10, b10 = *(const f32x4*)(t10 + 4);
            f32x4 a11 = *(const f32x4*)t11, b11 = *(const f32x4*)(t11 + 4);
#pragma unroll
            for (int i = 0; i < 4; i++) {
                float v  = w00 * a00[i] + w01 * a01[i] + w10 * a10[i] + w11 * a11[i];
                float v2 = w00 * b00[i] + w01 * b01[i] + w10 * b10[i] + w11 * b11[i];
                bfr[i] = f2bf(v);
                bfr[4 + i] = f2bf(v2);
            }
        } else {
#pragma unroll
            for (int i = 0; i < 8; i++) {
                const float* xc = xb + (size_t)(c0 + i) * HH * WW;
                float v = w00 * xc[o00] + w01 * xc[o01] + w10 * xc[o10] + w11 * xc[o11];
                bfr[i] = f2bf(v);
            }
        }
        const short* ap = w2 + (size_t)col * KQ + ch * 32 + (qg << 3);
        bf16x8 a0 = *(const bf16x8*)ap;
        bf16x8 a1 = *(const bf16x8*)(ap + 16 * KQ);
        bf16x8 a2 = *(const bf16x8*)(ap + 32 * KQ);
        bf16x8 a3 = *(const bf16x8*)(ap + 48 * KQ);
        acc0 = __builtin_amdgcn_mfma_f32_16x16x32_bf16(a0, bfr, acc0, 0, 0, 0);
        acc1 = __builtin_amdgcn_mfma_f32_16x16x32_bf16(a1, bfr, acc1, 0, 0, 0);
        acc2 = __builtin_amdgcn_mfma_f32_16x16x32_bf16(a2, bfr, acc2, 0, 0, 0);
        acc3 = __builtin_amdgcn_mfma_f32_16x16x32_bf16(a3, bfr, acc3, 0, 0, 0);
    }

    size_t ob = (size_t)b * OCC * HH * WW + (size_t)oh * WW + ow;
#pragma unroll
    for (int j = 0; j < 4; j++) {
        int r = (qg << 2) + j;
        out[ob + (size_t)r * HH * WW]        = acc0[j] + bias[r];
        out[ob + (size_t)(r + 16) * HH * WW] = acc1[j] + bias[r + 16];
        out[ob + (size_t)(r + 32) * HH * WW] = acc2[j] + bias[r + 32];
        out[ob + (size_t)(r + 48) * HH * WW] = acc3[j] + bias[r + 48];
    }
}

// ---------------- Fallback (round-1, all-f32, no ws) ----------------
__global__ __launch_bounds__(256)
void deform_fused_fb(const float* __restrict__ x,
                     const float* __restrict__ weight,
                     const float* __restrict__ bias,
                     const float* __restrict__ offset_w,
                     const float* __restrict__ offset_b,
                     const float* __restrict__ mask_w,
                     const float* __restrict__ mask_b,
                     float* __restrict__ out) {
    int p = blockIdx.x * 256 + threadIdx.x;
    int ow = p & (WW - 1);
    int oh = (p >> 7) & (HH - 1);
    int b = p >> 14;
    const float* xb = x + (size_t)b * CC * HH * WW;

    float acc[27];
#pragma unroll
    for (int j = 0; j < 18; j++) acc[j] = offset_b[j];
#pragma unroll
    for (int j = 0; j < 9; j++) acc[18 + j] = mask_b[j];

    for (int c = 0; c < CC; c++) {
        const float* xc = xb + c * HH * WW;
        float xv[9];
#pragma unroll
        for (int t = 0; t < 9; t++) {
            int iy = oh - 1 + t / 3;
            int ix = ow - 1 + t % 3;
            bool v = (iy >= 0) && (iy < HH) && (ix >= 0) && (ix < WW);
            xv[t] = v ? xc[iy * WW + ix] : 0.f;
        }
#pragma unroll
        for (int t = 0; t < 9; t++)
#pragma unroll
            for (int j = 0; j < 27; j++) {
                float wv = (j < 18) ? offset_w[(j * CC + c) * 9 + t]
                                    : mask_w[((j - 18) * CC + c) * 9 + t];
                acc[j] += xv[t] * wv;
            }
    }

    float acc2[OCC];
#pragma unroll
    for (int o = 0; o < OCC; o++) acc2[o] = 0.f;

#pragma unroll
    for (int k = 0; k < 9; k++) {
        float dy = acc[2 * k], dx = acc[2 * k + 1];
        float m = 1.f / (1.f + __expf(-acc[18 + k]));
        float py = (float)(oh - 1 + k / 3) + dy;
        float px = (float)(ow - 1 + k % 3) + dx;
        float y0f = floorf(py), x0f = floorf(px);
        float fy = py - y0f, fx = px - x0f;
        int y0 = (int)y0f, x0 = (int)x0f;
        int y1 = y0 + 1, x1 = x0 + 1;
        bool vy0 = (y0 >= 0) && (y0 < HH), vy1 = (y1 >= 0) && (y1 < HH);
        bool vx0 = (x0 >= 0) && (x0 < WW), vx1 = (x1 >= 0) && (x1 < WW);
        float w00 = (vy0 && vx0) ? (1.f - fy) * (1.f - fx) * m : 0.f;
        float w01 = (vy0 && vx1) ? (1.f - fy) * fx * m : 0.f;
        float w10 = (vy1 && vx0) ? fy * (1.f - fx) * m : 0.f;
        float w11 = (vy1 && vx1) ? fy * fx * m : 0.f;
        int iy0 = min(max(y0, 0), HH - 1), iy1 = min(max(y1, 0), HH - 1);
        int ix0 = min(max(x0, 0), WW - 1), ix1 = min(max(x1, 0), WW - 1);
        int o00 = iy0 * WW + ix0, o01 = iy0 * WW + ix1;
        int o10 = iy1 * WW + ix0, o11 = iy1 * WW + ix1;
        for (int c = 0; c < CC; c++) {
            const float* xc = xb + c * HH * WW;
            float v = w00 * xc[o00] + w01 * xc[o01] + w10 * xc[o10] + w11 * xc[o11];
#pragma unroll
            for (int o = 0; o < OCC; o++) acc2[o] += v * weight[(o * CC + c) * 9 + k];
        }
    }
    float* ob = out + (size_t)b * OCC * HH * WW + oh * WW + ow;
#pragma unroll
    for (int o = 0; o < OCC; o++) ob[(size_t)o * HH * WW] = acc2[o] + bias[o];
}

extern "C" void kernel_launch(void* const* d_in, const int* in_sizes, int n_in,
                              void* d_out, int out_size, void* d_ws, size_t ws_size,
                              hipStream_t stream) {
    const float* x        = (const float*)d_in[0];
    const float* weight   = (const float*)d_in[1];
    const float* bias     = (const float*)d_in[2];
    const float* offset_w = (const float*)d_in[3];
    const float* offset_b = (const float*)d_in[4];
    const float* mask_w   = (const float*)d_in[5];
    const float* mask_b   = (const float*)d_in[6];
    float* out = (float*)d_out;

    if (ws_size >= (size_t)WS_FULL) {
        float* xt = (float*)((char*)d_ws + XT_OFF);
        float* co = (float*)((char*)d_ws + CO_OFF);
        short* w1 = (short*)((char*)d_ws + W1_OFF);
        short* w2 = (short*)((char*)d_ws + W2_OFF);
        prep_weights<<<216, 256, 0, stream>>>(weight, offset_w, mask_w, w1, w2);
        transpose_x<<<BB * HH, 256, 0, stream>>>(x, xt);
        conv_mfma<true><<<NPIX / 64, 256, 0, stream>>>(xt, offset_b, mask_b, w1, co);
        deform_mfma<true><<<NPIX / 64, 256, 0, stream>>>(xt, bias, w2, co, out);
    } else if (ws_size >= (size_t)WS_MID) {
        float* co = (float*)((char*)d_ws + CO2_OFF);
        short* w1 = (short*)((char*)d_ws + W1B_OFF);
        short* w2 = (short*)((char*)d_ws + W2B_OFF);
        prep_weights<<<216, 256, 0, stream>>>(weight, offset_w, mask_w, w1, w2);
        conv_mfma<false><<<NPIX / 64, 256, 0, stream>>>(x, offset_b, mask_b, w1, co);
        deform_mfma<false><<<NPIX / 64, 256, 0, stream>>>(x, bias, w2, co, out);
    } else {
        deform_fused_fb<<<NPIX / 256, 256, 0, stream>>>(x, weight, bias, offset_w, offset_b,
                                                        mask_w, mask_b, out);
    }
}

// Round 4
// 262.783 us; speedup vs baseline: 1.4405x; 1.0713x over previous
//
#include <hip/hip_runtime.h>

#define HH 128
#define WW 128
#define CC 64
#define OCC 64
#define BB 8
#define NPIX (BB * HH * WW)   // 131072
#define KQ 576                // 9 * 64, q = k*64 + c

typedef __attribute__((ext_vector_type(4))) float f32x4;
typedef __attribute__((ext_vector_type(8))) short bf16x8;

// ---- ws layout (full path) ----
#define XT_OFF 0                         // xt [B][H][W][C] f32 = 33,554,432 B
#define W1_OFF 33554432                  // W1 [32][576] bf16   = 36,864 B
#define W2_OFF 33591296                  // W2 [64][576] bf16   = 73,728 B
#define WS_FULL (33591296 + 73728)

__device__ __forceinline__ short f2bf(float f) {
    union { float f; unsigned u; } v; v.f = f;
    unsigned r = v.u + 0x7FFF + ((v.u >> 16) & 1);   // RNE
    return (short)(r >> 16);
}

// ---------------- K0: pack weights to bf16, q = k*64 + c ----------------
__global__ void prep_weights(const float* __restrict__ weight,
                             const float* __restrict__ offset_w,
                             const float* __restrict__ mask_w,
                             short* __restrict__ w1, short* __restrict__ w2) {
    int tid = blockIdx.x * 256 + threadIdx.x;
    if (tid < 32 * KQ) {
        int q = tid % KQ, r = tid / KQ;
        int k = q >> 6, c = q & 63;
        float v = 0.f;
        if (r < 18)      v = offset_w[(r * CC + c) * 9 + k];
        else if (r < 27) v = mask_w[((r - 18) * CC + c) * 9 + k];
        w1[tid] = f2bf(v);
    } else {
        int u = tid - 32 * KQ;
        if (u < 64 * KQ) {
            int q = u % KQ, oc = u / KQ;
            int k = q >> 6, c = q & 63;
            w2[u] = f2bf(weight[(oc * CC + c) * 9 + k]);
        }
    }
}

// ---------------- K0b: NCHW -> NHWC transpose of x ----------------
__global__ __launch_bounds__(256) void transpose_x(
    const float* __restrict__ x, float* __restrict__ xt) {
    __shared__ float lds[128 * 65];
    int bh = blockIdx.x;           // b*128 + h
    int b = bh >> 7, h = bh & 127;
    const float* xr = x + ((size_t)b * CC * HH + h) * WW;
    int tid = threadIdx.x;
#pragma unroll
    for (int it = 0; it < 32; it++) {
        int e = it * 256 + tid;
        int c = e >> 7, w = e & 127;
        lds[w * 65 + c] = xr[(size_t)c * HH * WW + w];
    }
    __syncthreads();
    float* otr = xt + (size_t)bh * WW * CC;
#pragma unroll
    for (int it = 0; it < 32; it++) {
        int e = it * 256 + tid;
        otr[e] = lds[(e >> 6) * 65 + (e & 63)];
    }
}

// ---------------- K1: fused offset/mask conv + deformable einsum ----------------
// Block = 64 consecutive pixels (4 waves x 16). XCD-chunked swizzle: hw bid%8
// picks the image, so each XCD's 256 resident blocks share one 4MB image in L2.
__global__ __launch_bounds__(256) void fused_mfma(
    const float* __restrict__ xt,
    const float* __restrict__ offset_b,
    const float* __restrict__ mask_b,
    const float* __restrict__ bias,
    const short* __restrict__ w1,
    const short* __restrict__ w2,
    float* __restrict__ out) {
    __shared__ float colds[64 * 33];           // co[pixel][ch], stride 33: conflict-free

    int lane = threadIdx.x & 63;
    int wv = threadIdx.x >> 6;
    int bid = blockIdx.x;
    int logical = (bid & 7) * 256 + (bid >> 3);   // 2048 blocks, 256 per image
    int col = lane & 15;
    int qg = lane >> 4;
    int p = logical * 64 + wv * 16 + col;
    int ow = p & (WW - 1);
    int oh = (p >> 7) & (HH - 1);
    int b = p >> 14;
    const float* xb = xt + (size_t)b * CC * HH * WW;   // NHWC

    // ---- Phase A: 3x3 conv -> 27 offset/mask channels for this block's pixels
    f32x4 acc0 = {0.f,0.f,0.f,0.f}, acc1 = {0.f,0.f,0.f,0.f};
#pragma unroll 2
    for (int ch = 0; ch < 18; ch++) {
        int k = ch >> 1;
        int c0 = ((ch & 1) << 5) + (qg << 3);
        int iy = oh - 1 + k / 3;
        int ix = ow - 1 + (k - (k / 3) * 3);
        bool vv = (iy >= 0) && (iy < HH) && (ix >= 0) && (ix < WW);
        f32x4 va = {0.f,0.f,0.f,0.f}, vb = {0.f,0.f,0.f,0.f};
        if (vv) {
            const float* tp = xb + (size_t)(iy * WW + ix) * CC + c0;
            va = *(const f32x4*)tp;
            vb = *(const f32x4*)(tp + 4);
        }
        bf16x8 bfr;
#pragma unroll
        for (int i = 0; i < 4; i++) { bfr[i] = f2bf(va[i]); bfr[4 + i] = f2bf(vb[i]); }
        const short* ap = w1 + (size_t)col * KQ + ch * 32 + (qg << 3);
        bf16x8 a0 = *(const bf16x8*)ap;
        bf16x8 a1 = *(const bf16x8*)(ap + 16 * KQ);
        acc0 = __builtin_amdgcn_mfma_f32_16x16x32_bf16(a0, bfr, acc0, 0, 0, 0);
        acc1 = __builtin_amdgcn_mfma_f32_16x16x32_bf16(a1, bfr, acc1, 0, 0, 0);
    }
    {
        int pl = wv * 16 + col;
#pragma unroll
        for (int j = 0; j < 4; j++) {
            int r0 = (qg << 2) + j;
            int r1 = 16 + r0;
            float b1 = (r1 < 18) ? offset_b[r1] : (r1 < 27 ? mask_b[r1 - 18] : 0.f);
            colds[pl * 33 + r0] = acc0[j] + offset_b[r0];
            colds[pl * 33 + r1] = acc1[j] + b1;
        }
    }
    __syncthreads();

    // ---- Phase B: deformable gather + einsum
    f32x4 acc2 = {0.f,0.f,0.f,0.f}, acc3 = {0.f,0.f,0.f,0.f};
    acc0 = (f32x4){0.f,0.f,0.f,0.f};
    acc1 = (f32x4){0.f,0.f,0.f,0.f};
    const float* cop = &colds[(wv * 16 + col) * 33];

    float w00 = 0.f, w01 = 0.f, w10 = 0.f, w11 = 0.f;
    int o00 = 0, o01 = 0, o10 = 0, o11 = 0;

#pragma unroll 2
    for (int ch = 0; ch < 18; ch++) {
        if ((ch & 1) == 0) {
            int k = ch >> 1;
            float dy = cop[2 * k];
            float dx = cop[2 * k + 1];
            float mr = cop[18 + k];
            float m = 1.f / (1.f + __expf(-mr));
            float py = (float)(oh - 1 + k / 3) + dy;
            float px = (float)(ow - 1 + (k - (k / 3) * 3)) + dx;
            float y0f = floorf(py), x0f = floorf(px);
            float fy = py - y0f, fx = px - x0f;
            int y0 = (int)y0f, xq = (int)x0f;
            int y1 = y0 + 1, x1 = xq + 1;
            bool vy0 = (y0 >= 0) && (y0 < HH), vy1 = (y1 >= 0) && (y1 < HH);
            bool vx0 = (xq >= 0) && (xq < WW), vx1 = (x1 >= 0) && (x1 < WW);
            w00 = (vy0 && vx0) ? (1.f - fy) * (1.f - fx) * m : 0.f;
            w01 = (vy0 && vx1) ? (1.f - fy) * fx * m : 0.f;
            w10 = (vy1 && vx0) ? fy * (1.f - fx) * m : 0.f;
            w11 = (vy1 && vx1) ? fy * fx * m : 0.f;
            int iy0 = min(max(y0, 0), HH - 1), iy1 = min(max(y1, 0), HH - 1);
            int ix0 = min(max(xq, 0), WW - 1), ix1 = min(max(x1, 0), WW - 1);
            o00 = iy0 * WW + ix0; o01 = iy0 * WW + ix1;
            o10 = iy1 * WW + ix0; o11 = iy1 * WW + ix1;
        }
        int c0 = ((ch & 1) << 5) + (qg << 3);
        const float* t00 = xb + (size_t)o00 * CC + c0;
        const float* t01 = xb + (size_t)o01 * CC + c0;
        const float* t10 = xb + (size_t)o10 * CC + c0;
        const float* t11 = xb + (size_t)o11 * CC + c0;
        f32x4 a00 = *(const f32x4*)t00, b00 = *(const f32x4*)(t00 + 4);
        f32x4 a01 = *(const f32x4*)t01, b01 = *(const f32x4*)(t01 + 4);
        f32x4 a10 = *(const f32x4*)t10, b10 = *(const f32x4*)(t10 + 4);
        f32x4 a11 = *(const f32x4*)t11, b11 = *(const f32x4*)(t11 + 4);
        bf16x8 bfr;
#pragma unroll
        for (int i = 0; i < 4; i++) {
            float v  = w00 * a00[i] + w01 * a01[i] + w10 * a10[i] + w11 * a11[i];
            float v2 = w00 * b00[i] + w01 * b01[i] + w10 * b10[i] + w11 * b11[i];
            bfr[i] = f2bf(v);
            bfr[4 + i] = f2bf(v2);
        }
        const short* ap = w2 + (size_t)col * KQ + ch * 32 + (qg << 3);
        bf16x8 a0 = *(const bf16x8*)ap;
        bf16x8 a1 = *(const bf16x8*)(ap + 16 * KQ);
        bf16x8 a2 = *(const bf16x8*)(ap + 32 * KQ);
        bf16x8 a3 = *(const bf16x8*)(ap + 48 * KQ);
        acc0 = __builtin_amdgcn_mfma_f32_16x16x32_bf16(a0, bfr, acc0, 0, 0, 0);
        acc1 = __builtin_amdgcn_mfma_f32_16x16x32_bf16(a1, bfr, acc1, 0, 0, 0);
        acc2 = __builtin_amdgcn_mfma_f32_16x16x32_bf16(a2, bfr, acc2, 0, 0, 0);
        acc3 = __builtin_amdgcn_mfma_f32_16x16x32_bf16(a3, bfr, acc3, 0, 0, 0);
    }

    size_t ob = (size_t)b * OCC * HH * WW + (size_t)oh * WW + ow;
#pragma unroll
    for (int j = 0; j < 4; j++) {
        int r = (qg << 2) + j;
        out[ob + (size_t)r * HH * WW]        = acc0[j] + bias[r];
        out[ob + (size_t)(r + 16) * HH * WW] = acc1[j] + bias[r + 16];
        out[ob + (size_t)(r + 32) * HH * WW] = acc2[j] + bias[r + 32];
        out[ob + (size_t)(r + 48) * HH * WW] = acc3[j] + bias[r + 48];
    }
}

// ---------------- Fallback (round-1, all-f32, no ws) ----------------
__global__ __launch_bounds__(256)
void deform_fused_fb(const float* __restrict__ x,
                     const float* __restrict__ weight,
                     const float* __restrict__ bias,
                     const float* __restrict__ offset_w,
                     const float* __restrict__ offset_b,
                     const float* __restrict__ mask_w,
                     const float* __restrict__ mask_b,
                     float* __restrict__ out) {
    int p = blockIdx.x * 256 + threadIdx.x;
    int ow = p & (WW - 1);
    int oh = (p >> 7) & (HH - 1);
    int b = p >> 14;
    const float* xb = x + (size_t)b * CC * HH * WW;

    float acc[27];
#pragma unroll
    for (int j = 0; j < 18; j++) acc[j] = offset_b[j];
#pragma unroll
    for (int j = 0; j < 9; j++) acc[18 + j] = mask_b[j];

    for (int c = 0; c < CC; c++) {
        const float* xc = xb + c * HH * WW;
        float xv[9];
#pragma unroll
        for (int t = 0; t < 9; t++) {
            int iy = oh - 1 + t / 3;
            int ix = ow - 1 + t % 3;
            bool v = (iy >= 0) && (iy < HH) && (ix >= 0) && (ix < WW);
            xv[t] = v ? xc[iy * WW + ix] : 0.f;
        }
#pragma unroll
        for (int t = 0; t < 9; t++)
#pragma unroll
            for (int j = 0; j < 27; j++) {
                float wv = (j < 18) ? offset_w[(j * CC + c) * 9 + t]
                                    : mask_w[((j - 18) * CC + c) * 9 + t];
                acc[j] += xv[t] * wv;
            }
    }

    float acc2[OCC];
#pragma unroll
    for (int o = 0; o < OCC; o++) acc2[o] = 0.f;

#pragma unroll
    for (int k = 0; k < 9; k++) {
        float dy = acc[2 * k], dx = acc[2 * k + 1];
        float m = 1.f / (1.f + __expf(-acc[18 + k]));
        float py = (float)(oh - 1 + k / 3) + dy;
        float px = (float)(ow - 1 + k % 3) + dx;
        float y0f = floorf(py), x0f = floorf(px);
        float fy = py - y0f, fx = px - x0f;
        int y0 = (int)y0f, x0 = (int)x0f;
        int y1 = y0 + 1, x1 = x0 + 1;
        bool vy0 = (y0 >= 0) && (y0 < HH), vy1 = (y1 >= 0) && (y1 < HH);
        bool vx0 = (x0 >= 0) && (x0 < WW), vx1 = (x1 >= 0) && (x1 < WW);
        float w00 = (vy0 && vx0) ? (1.f - fy) * (1.f - fx) * m : 0.f;
        float w01 = (vy0 && vx1) ? (1.f - fy) * fx * m : 0.f;
        float w10 = (vy1 && vx0) ? fy * (1.f - fx) * m : 0.f;
        float w11 = (vy1 && vx1) ? fy * fx * m : 0.f;
        int iy0 = min(max(y0, 0), HH - 1), iy1 = min(max(y1, 0), HH - 1);
        int ix0 = min(max(x0, 0), WW - 1), ix1 = min(max(x1, 0), WW - 1);
        int o00 = iy0 * WW + ix0, o01 = iy0 * WW + ix1;
        int o10 = iy1 * WW + ix0, o11 = iy1 * WW + ix1;
        for (int c = 0; c < CC; c++) {
            const float* xc = xb + c * HH * WW;
            float v = w00 * xc[o00] + w01 * xc[o01] + w10 * xc[o10] + w11 * xc[o11];
#pragma unroll
            for (int o = 0; o < OCC; o++) acc2[o] += v * weight[(o * CC + c) * 9 + k];
        }
    }
    float* ob = out + (size_t)b * OCC * HH * WW + oh * WW + ow;
#pragma unroll
    for (int o = 0; o < OCC; o++) ob[(size_t)o * HH * WW] = acc2[o] + bias[o];
}

extern "C" void kernel_launch(void* const* d_in, const int* in_sizes, int n_in,
                              void* d_out, int out_size, void* d_ws, size_t ws_size,
                              hipStream_t stream) {
    const float* x        = (const float*)d_in[0];
    const float* weight   = (const float*)d_in[1];
    const float* bias     = (const float*)d_in[2];
    const float* offset_w = (const float*)d_in[3];
    const float* offset_b = (const float*)d_in[4];
    const float* mask_w   = (const float*)d_in[5];
    const float* mask_b   = (const float*)d_in[6];
    float* out = (float*)d_out;

    if (ws_size >= (size_t)WS_FULL) {
        float* xt = (float*)((char*)d_ws + XT_OFF);
        short* w1 = (short*)((char*)d_ws + W1_OFF);
        short* w2 = (short*)((char*)d_ws + W2_OFF);
        prep_weights<<<216, 256, 0, stream>>>(weight, offset_w, mask_w, w1, w2);
        transpose_x<<<BB * HH, 256, 0, stream>>>(x, xt);
        fused_mfma<<<NPIX / 64, 256, 0, stream>>>(xt, offset_b, mask_b, bias, w1, w2, out);
    } else {
        deform_fused_fb<<<NPIX / 256, 256, 0, stream>>>(x, weight, bias, offset_w, offset_b,
                                                        mask_w, mask_b, out);
    }
}

// Round 5
// 121.812 us; speedup vs baseline: 3.1076x; 2.1573x over previous
//
#include <hip/hip_runtime.h>

#define HH 128
#define WW 128
#define CC 64
#define OCC 64
#define BB 8
#define NPIX (BB * HH * WW)   // 131072

typedef __attribute__((ext_vector_type(4))) float f32x4;
typedef __attribute__((ext_vector_type(8))) short bf16x8;

// ---- ws layout (full path) ----
#define XT_OFF 0                         // xt [B][H][W][C] bf16 = 16,777,216 B
#define W1F_OFF 16777216                 // w1f [2][18][64][8] bf16 = 36,864 B
#define W2F_OFF 16814080                 // w2f [4][18][64][8] bf16 = 73,728 B
#define WS_FULL (16814080 + 73728)

__device__ __forceinline__ short f2bf(float f) {
    union { float f; unsigned u; } v; v.f = f;
    unsigned r = v.u + 0x7FFF + ((v.u >> 16) & 1);   // RNE
    return (short)(r >> 16);
}
__device__ __forceinline__ float bf2f(short s) {
    union { unsigned u; float f; } v;
    v.u = ((unsigned)(unsigned short)s) << 16;
    return v.f;
}

// ---------------- K0: pack weights to MFMA-fragment order ----------------
// w{1,2}f[tile][ch][lane][i] = W[tile*16 + (lane&15)][q = ch*32 + (lane>>4)*8 + i]
// (q = k*64 + c). A wave's A-fragment load is then lane-linear: 1KB coalesced.
__global__ void prep_weights(const float* __restrict__ weight,
                             const float* __restrict__ offset_w,
                             const float* __restrict__ mask_w,
                             short* __restrict__ w1f, short* __restrict__ w2f) {
    int tid = blockIdx.x * 256 + threadIdx.x;
    if (tid < 2 * 18 * 64 * 8) {                 // 18432
        int i = tid & 7, lane = (tid >> 3) & 63, ch = (tid >> 9) % 18, tile = tid / (18 * 512);
        int r = tile * 16 + (lane & 15);
        int q = ch * 32 + ((lane >> 4) << 3) + i;
        int k = q >> 6, c = q & 63;
        float v = 0.f;
        if (r < 18)      v = offset_w[(r * CC + c) * 9 + k];
        else if (r < 27) v = mask_w[((r - 18) * CC + c) * 9 + k];
        w1f[tid] = f2bf(v);
    } else {
        int u = tid - 18432;
        if (u < 4 * 18 * 64 * 8) {               // 36864
            int i = u & 7, lane = (u >> 3) & 63, ch = (u >> 9) % 18, tile = u / (18 * 512);
            int oc = tile * 16 + (lane & 15);
            int q = ch * 32 + ((lane >> 4) << 3) + i;
            int k = q >> 6, c = q & 63;
            w2f[u] = f2bf(weight[(oc * CC + c) * 9 + k]);
        }
    }
}

// ---------------- K0b: NCHW f32 -> NHWC bf16 transpose of x ----------------
__global__ __launch_bounds__(256) void transpose_x(
    const float* __restrict__ x, unsigned short* __restrict__ xt) {
    __shared__ float lds[128 * 65];
    int bh = blockIdx.x;           // b*128 + h
    int b = bh >> 7, h = bh & 127;
    const float* xr = x + ((size_t)b * CC * HH + h) * WW;
    int tid = threadIdx.x;
#pragma unroll
    for (int it = 0; it < 32; it++) {
        int e = it * 256 + tid;
        int c = e >> 7, w = e & 127;
        lds[w * 65 + c] = xr[(size_t)c * HH * WW + w];
    }
    __syncthreads();
    unsigned* otr = (unsigned*)(xt + (size_t)bh * WW * CC);   // packed bf16 pairs
#pragma unroll
    for (int it = 0; it < 16; it++) {
        int e = it * 256 + tid;            // pair index: w*32 + cp
        int w = e >> 5, cp = e & 31;
        unsigned lo = (unsigned short)f2bf(lds[w * 65 + 2 * cp]);
        unsigned hi = (unsigned short)f2bf(lds[w * 65 + 2 * cp + 1]);
        otr[e] = lo | (hi << 16);
    }
}

// ---------------- K1: fused conv + deformable einsum (bf16 NHWC) ----------------
__global__ __launch_bounds__(256) void fused_mfma(
    const unsigned short* __restrict__ xt,
    const float* __restrict__ offset_b,
    const float* __restrict__ mask_b,
    const float* __restrict__ bias,
    const short* __restrict__ w1f,
    const short* __restrict__ w2f,
    float* __restrict__ out) {
    __shared__ float colds[64 * 33];

    int lane = threadIdx.x & 63;
    int wv = threadIdx.x >> 6;
    int bid = blockIdx.x;
    int logical = (bid & 7) * 256 + (bid >> 3);   // XCD-chunked: bid%8 -> image
    int col = lane & 15;
    int qg = lane >> 4;
    int p = logical * 64 + wv * 16 + col;
    int ow = p & (WW - 1);
    int oh = (p >> 7) & (HH - 1);
    int b = p >> 14;
    const unsigned short* xb = xt + (size_t)b * CC * HH * WW;   // NHWC bf16

    // ---- Phase A: 3x3 conv -> 27 offset/mask channels
    f32x4 acc0 = {0.f,0.f,0.f,0.f}, acc1 = {0.f,0.f,0.f,0.f};
#pragma unroll
    for (int ch = 0; ch < 18; ch++) {
        int k = ch >> 1;
        int c0 = ((ch & 1) << 5) + (qg << 3);
        int iy = oh - 1 + k / 3;
        int ix = ow - 1 + (k - (k / 3) * 3);
        bool vv = (iy >= 0) && (iy < HH) && (ix >= 0) && (ix < WW);
        bf16x8 bfr = {0,0,0,0,0,0,0,0};
        if (vv) bfr = *(const bf16x8*)(xb + (size_t)(iy * WW + ix) * CC + c0);
        bf16x8 a0 = *(const bf16x8*)(w1f + ((size_t)(0 * 18 + ch) * 64 + lane) * 8);
        bf16x8 a1 = *(const bf16x8*)(w1f + ((size_t)(1 * 18 + ch) * 64 + lane) * 8);
        acc0 = __builtin_amdgcn_mfma_f32_16x16x32_bf16(a0, bfr, acc0, 0, 0, 0);
        acc1 = __builtin_amdgcn_mfma_f32_16x16x32_bf16(a1, bfr, acc1, 0, 0, 0);
    }
    {
        int pl = wv * 16 + col;
#pragma unroll
        for (int j = 0; j < 4; j++) {
            int r0 = (qg << 2) + j;
            int r1 = 16 + r0;
            float b1 = (r1 < 18) ? offset_b[r1] : (r1 < 27 ? mask_b[r1 - 18] : 0.f);
            colds[pl * 33 + r0] = acc0[j] + offset_b[r0];
            colds[pl * 33 + r1] = acc1[j] + b1;
        }
    }
    __syncthreads();

    // ---- Hoist all 9 taps: bilinear weights + clamped offsets (static arrays)
    const float* cop = &colds[(wv * 16 + col) * 33];
    float w00a[9], w01a[9], w10a[9], w11a[9];
    int o00a[9], o01a[9], o10a[9], o11a[9];
#pragma unroll
    for (int k = 0; k < 9; k++) {
        float dy = cop[2 * k];
        float dx = cop[2 * k + 1];
        float mr = cop[18 + k];
        float m = 1.f / (1.f + __expf(-mr));
        float py = (float)(oh - 1 + k / 3) + dy;
        float px = (float)(ow - 1 + (k - (k / 3) * 3)) + dx;
        float y0f = floorf(py), x0f = floorf(px);
        float fy = py - y0f, fx = px - x0f;
        int y0 = (int)y0f, x0 = (int)x0f;
        int y1 = y0 + 1, x1 = x0 + 1;
        bool vy0 = (y0 >= 0) && (y0 < HH), vy1 = (y1 >= 0) && (y1 < HH);
        bool vx0 = (x0 >= 0) && (x0 < WW), vx1 = (x1 >= 0) && (x1 < WW);
        w00a[k] = (vy0 && vx0) ? (1.f - fy) * (1.f - fx) * m : 0.f;
        w01a[k] = (vy0 && vx1) ? (1.f - fy) * fx * m : 0.f;
        w10a[k] = (vy1 && vx0) ? fy * (1.f - fx) * m : 0.f;
        w11a[k] = (vy1 && vx1) ? fy * fx * m : 0.f;
        int iy0 = min(max(y0, 0), HH - 1), iy1 = min(max(y1, 0), HH - 1);
        int ix0 = min(max(x0, 0), WW - 1), ix1 = min(max(x1, 0), WW - 1);
        o00a[k] = iy0 * WW + ix0; o01a[k] = iy0 * WW + ix1;
        o10a[k] = iy1 * WW + ix0; o11a[k] = iy1 * WW + ix1;
    }

    // ---- Phase B: gather + einsum, fully unrolled, addresses dependency-free
    f32x4 acc2 = {0.f,0.f,0.f,0.f}, acc3 = {0.f,0.f,0.f,0.f};
    acc0 = (f32x4){0.f,0.f,0.f,0.f};
    acc1 = (f32x4){0.f,0.f,0.f,0.f};
#pragma unroll
    for (int ch = 0; ch < 18; ch++) {
        int k = ch >> 1;
        int c0 = ((ch & 1) << 5) + (qg << 3);
        bf16x8 r00 = *(const bf16x8*)(xb + (size_t)o00a[k] * CC + c0);
        bf16x8 r01 = *(const bf16x8*)(xb + (size_t)o01a[k] * CC + c0);
        bf16x8 r10 = *(const bf16x8*)(xb + (size_t)o10a[k] * CC + c0);
        bf16x8 r11 = *(const bf16x8*)(xb + (size_t)o11a[k] * CC + c0);
        bf16x8 bfr;
#pragma unroll
        for (int i = 0; i < 8; i++) {
            float v = w00a[k] * bf2f(r00[i]) + w01a[k] * bf2f(r01[i])
                    + w10a[k] * bf2f(r10[i]) + w11a[k] * bf2f(r11[i]);
            bfr[i] = f2bf(v);
        }
        bf16x8 a0 = *(const bf16x8*)(w2f + ((size_t)(0 * 18 + ch) * 64 + lane) * 8);
        bf16x8 a1 = *(const bf16x8*)(w2f + ((size_t)(1 * 18 + ch) * 64 + lane) * 8);
        bf16x8 a2 = *(const bf16x8*)(w2f + ((size_t)(2 * 18 + ch) * 64 + lane) * 8);
        bf16x8 a3 = *(const bf16x8*)(w2f + ((size_t)(3 * 18 + ch) * 64 + lane) * 8);
        acc0 = __builtin_amdgcn_mfma_f32_16x16x32_bf16(a0, bfr, acc0, 0, 0, 0);
        acc1 = __builtin_amdgcn_mfma_f32_16x16x32_bf16(a1, bfr, acc1, 0, 0, 0);
        acc2 = __builtin_amdgcn_mfma_f32_16x16x32_bf16(a2, bfr, acc2, 0, 0, 0);
        acc3 = __builtin_amdgcn_mfma_f32_16x16x32_bf16(a3, bfr, acc3, 0, 0, 0);
    }

    size_t ob = (size_t)b * OCC * HH * WW + (size_t)oh * WW + ow;
#pragma unroll
    for (int j = 0; j < 4; j++) {
        int r = (qg << 2) + j;
        out[ob + (size_t)r * HH * WW]        = acc0[j] + bias[r];
        out[ob + (size_t)(r + 16) * HH * WW] = acc1[j] + bias[r + 16];
        out[ob + (size_t)(r + 32) * HH * WW] = acc2[j] + bias[r + 32];
        out[ob + (size_t)(r + 48) * HH * WW] = acc3[j] + bias[r + 48];
    }
}

// ---------------- Fallback (round-1, all-f32, no ws) ----------------
__global__ __launch_bounds__(256)
void deform_fused_fb(const float* __restrict__ x,
                     const float* __restrict__ weight,
                     const float* __restrict__ bias,
                     const float* __restrict__ offset_w,
                     const float* __restrict__ offset_b,
                     const float* __restrict__ mask_w,
                     const float* __restrict__ mask_b,
                     float* __restrict__ out) {
    int p = blockIdx.x * 256 + threadIdx.x;
    int ow = p & (WW - 1);
    int oh = (p >> 7) & (HH - 1);
    int b = p >> 14;
    const float* xb = x + (size_t)b * CC * HH * WW;

    float acc[27];
#pragma unroll
    for (int j = 0; j < 18; j++) acc[j] = offset_b[j];
#pragma unroll
    for (int j = 0; j < 9; j++) acc[18 + j] = mask_b[j];

    for (int c = 0; c < CC; c++) {
        const float* xc = xb + c * HH * WW;
        float xv[9];
#pragma unroll
        for (int t = 0; t < 9; t++) {
            int iy = oh - 1 + t / 3;
            int ix = ow - 1 + t % 3;
            bool v = (iy >= 0) && (iy < HH) && (ix >= 0) && (ix < WW);
            xv[t] = v ? xc[iy * WW + ix] : 0.f;
        }
#pragma unroll
        for (int t = 0; t < 9; t++)
#pragma unroll
            for (int j = 0; j < 27; j++) {
                float wv = (j < 18) ? offset_w[(j * CC + c) * 9 + t]
                                    : mask_w[((j - 18) * CC + c) * 9 + t];
                acc[j] += xv[t] * wv;
            }
    }

    float acc2[OCC];
#pragma unroll
    for (int o = 0; o < OCC; o++) acc2[o] = 0.f;

#pragma unroll
    for (int k = 0; k < 9; k++) {
        float dy = acc[2 * k], dx = acc[2 * k + 1];
        float m = 1.f / (1.f + __expf(-acc[18 + k]));
        float py = (float)(oh - 1 + k / 3) + dy;
        float px = (float)(ow - 1 + k % 3) + dx;
        float y0f = floorf(py), x0f = floorf(px);
        float fy = py - y0f, fx = px - x0f;
        int y0 = (int)y0f, x0 = (int)x0f;
        int y1 = y0 + 1, x1 = x0 + 1;
        bool vy0 = (y0 >= 0) && (y0 < HH), vy1 = (y1 >= 0) && (y1 < HH);
        bool vx0 = (x0 >= 0) && (x0 < WW), vx1 = (x1 >= 0) && (x1 < WW);
        float w00 = (vy0 && vx0) ? (1.f - fy) * (1.f - fx) * m : 0.f;
        float w01 = (vy0 && vx1) ? (1.f - fy) * fx * m : 0.f;
        float w10 = (vy1 && vx0) ? fy * (1.f - fx) * m : 0.f;
        float w11 = (vy1 && vx1) ? fy * fx * m : 0.f;
        int iy0 = min(max(y0, 0), HH - 1), iy1 = min(max(y1, 0), HH - 1);
        int ix0 = min(max(x0, 0), WW - 1), ix1 = min(max(x1, 0), WW - 1);
        int o00 = iy0 * WW + ix0, o01 = iy0 * WW + ix1;
        int o10 = iy1 * WW + ix0, o11 = iy1 * WW + ix1;
        for (int c = 0; c < CC; c++) {
            const float* xc = xb + c * HH * WW;
            float v = w00 * xc[o00] + w01 * xc[o01] + w10 * xc[o10] + w11 * xc[o11];
#pragma unroll
            for (int o = 0; o < OCC; o++) acc2[o] += v * weight[(o * CC + c) * 9 + k];
        }
    }
    float* ob = out + (size_t)b * OCC * HH * WW + oh * WW + ow;
#pragma unroll
    for (int o = 0; o < OCC; o++) ob[(size_t)o * HH * WW] = acc2[o] + bias[o];
}

extern "C" void kernel_launch(void* const* d_in, const int* in_sizes, int n_in,
                              void* d_out, int out_size, void* d_ws, size_t ws_size,
                              hipStream_t stream) {
    const float* x        = (const float*)d_in[0];
    const float* weight   = (const float*)d_in[1];
    const float* bias     = (const float*)d_in[2];
    const float* offset_w = (const float*)d_in[3];
    const float* offset_b = (const float*)d_in[4];
    const float* mask_w   = (const float*)d_in[5];
    const float* mask_b   = (const float*)d_in[6];
    float* out = (float*)d_out;

    if (ws_size >= (size_t)WS_FULL) {
        unsigned short* xt = (unsigned short*)((char*)d_ws + XT_OFF);
        short* w1f = (short*)((char*)d_ws + W1F_OFF);
        short* w2f = (short*)((char*)d_ws + W2F_OFF);
        prep_weights<<<216, 256, 0, stream>>>(weight, offset_w, mask_w, w1f, w2f);
        transpose_x<<<BB * HH, 256, 0, stream>>>(x, xt);
        fused_mfma<<<NPIX / 64, 256, 0, stream>>>(xt, offset_b, mask_b, bias, w1f, w2f, out);
    } else {
        deform_fused_fb<<<NPIX / 256, 256, 0, stream>>>(x, weight, bias, offset_w, offset_b,
                                                        mask_w, mask_b, out);
    }
}

// Round 6
// 121.118 us; speedup vs baseline: 3.1254x; 1.0057x over previous
//
#include <hip/hip_runtime.h>

#define HH 128
#define WW 128
#define CC 64
#define OCC 64
#define BB 8
#define NPIX (BB * HH * WW)   // 131072

typedef __attribute__((ext_vector_type(4))) float f32x4;
typedef __attribute__((ext_vector_type(2))) float f32x2;
typedef __attribute__((ext_vector_type(8))) short bf16x8;
typedef __attribute__((ext_vector_type(4))) unsigned u32x4;
typedef __attribute__((ext_vector_type(4))) int i32x4;

// ---- ws layout (full path) ----
#define XT_OFF 0                         // xt [B][H][W][C] bf16 = 16,777,216 B
#define W1F_OFF 16777216                 // w1f [2][18][64][8] bf16 = 36,864 B
#define W2F_OFF 16814080                 // w2f [4][18][64][8] bf16 = 73,728 B
#define WS_FULL (16814080 + 73728)

__device__ __forceinline__ short f2bf(float f) {
    union { float f; unsigned u; } v; v.f = f;
    unsigned r = v.u + 0x7FFF + ((v.u >> 16) & 1);   // RNE
    return (short)(r >> 16);
}

__device__ __forceinline__ unsigned cvtpk_bf16(float lo, float hi) {
    unsigned r;
    asm("v_cvt_pk_bf16_f32 %0, %1, %2" : "=v"(r) : "v"(lo), "v"(hi));
    return r;
}

// Packed bilinear: 8 channels from 4 corner fragments, weights w[0..3].
__device__ __forceinline__ bf16x8 bilerp8(bf16x8 r00, bf16x8 r01, bf16x8 r10, bf16x8 r11,
                                          f32x4 w) {
    u32x4 u00 = __builtin_bit_cast(u32x4, r00);
    u32x4 u01 = __builtin_bit_cast(u32x4, r01);
    u32x4 u10 = __builtin_bit_cast(u32x4, r10);
    u32x4 u11 = __builtin_bit_cast(u32x4, r11);
    u32x4 res;
#pragma unroll
    for (int j = 0; j < 4; j++) {
        f32x2 a, acc;
        a[0] = __builtin_bit_cast(float, (unsigned)(u00[j] << 16));
        a[1] = __builtin_bit_cast(float, (unsigned)(u00[j] & 0xFFFF0000u));
        acc = a * w[0];
        a[0] = __builtin_bit_cast(float, (unsigned)(u01[j] << 16));
        a[1] = __builtin_bit_cast(float, (unsigned)(u01[j] & 0xFFFF0000u));
        acc += a * w[1];
        a[0] = __builtin_bit_cast(float, (unsigned)(u10[j] << 16));
        a[1] = __builtin_bit_cast(float, (unsigned)(u10[j] & 0xFFFF0000u));
        acc += a * w[2];
        a[0] = __builtin_bit_cast(float, (unsigned)(u11[j] << 16));
        a[1] = __builtin_bit_cast(float, (unsigned)(u11[j] & 0xFFFF0000u));
        acc += a * w[3];
        res[j] = cvtpk_bf16(acc[0], acc[1]);
    }
    return __builtin_bit_cast(bf16x8, res);
}

// ---------------- K0: pack weights to MFMA-fragment order ----------------
__global__ void prep_weights(const float* __restrict__ weight,
                             const float* __restrict__ offset_w,
                             const float* __restrict__ mask_w,
                             short* __restrict__ w1f, short* __restrict__ w2f) {
    int tid = blockIdx.x * 256 + threadIdx.x;
    if (tid < 2 * 18 * 64 * 8) {                 // 18432
        int i = tid & 7, lane = (tid >> 3) & 63, ch = (tid >> 9) % 18, tile = tid / (18 * 512);
        int r = tile * 16 + (lane & 15);
        int q = ch * 32 + ((lane >> 4) << 3) + i;
        int k = q >> 6, c = q & 63;
        float v = 0.f;
        if (r < 18)      v = offset_w[(r * CC + c) * 9 + k];
        else if (r < 27) v = mask_w[((r - 18) * CC + c) * 9 + k];
        w1f[tid] = f2bf(v);
    } else {
        int u = tid - 18432;
        if (u < 4 * 18 * 64 * 8) {               // 36864
            int i = u & 7, lane = (u >> 3) & 63, ch = (u >> 9) % 18, tile = u / (18 * 512);
            int oc = tile * 16 + (lane & 15);
            int q = ch * 32 + ((lane >> 4) << 3) + i;
            int k = q >> 6, c = q & 63;
            w2f[u] = f2bf(weight[(oc * CC + c) * 9 + k]);
        }
    }
}

// ---------------- K0b: NCHW f32 -> NHWC bf16 transpose of x ----------------
__global__ __launch_bounds__(256) void transpose_x(
    const float* __restrict__ x, unsigned short* __restrict__ xt) {
    __shared__ float lds[128 * 65];
    int bh = blockIdx.x;           // b*128 + h
    int b = bh >> 7, h = bh & 127;
    const float* xr = x + ((size_t)b * CC * HH + h) * WW;
    int tid = threadIdx.x;
#pragma unroll
    for (int it = 0; it < 32; it++) {
        int e = it * 256 + tid;
        int c = e >> 7, w = e & 127;
        lds[w * 65 + c] = xr[(size_t)c * HH * WW + w];
    }
    __syncthreads();
    unsigned* otr = (unsigned*)(xt + (size_t)bh * WW * CC);   // packed bf16 pairs
#pragma unroll
    for (int it = 0; it < 16; it++) {
        int e = it * 256 + tid;            // pair index: w*32 + cp
        int w = e >> 5, cp = e & 31;
        unsigned lo = (unsigned short)f2bf(lds[w * 65 + 2 * cp]);
        unsigned hi = (unsigned short)f2bf(lds[w * 65 + 2 * cp + 1]);
        otr[e] = lo | (hi << 16);
    }
}

// ---------------- K1: fused conv + deformable einsum ----------------
__global__ __launch_bounds__(256) void fused_mfma(
    const unsigned short* __restrict__ xt,
    const float* __restrict__ offset_b,
    const float* __restrict__ mask_b,
    const float* __restrict__ bias,
    const short* __restrict__ w1f,
    const short* __restrict__ w2f,
    float* __restrict__ out) {
    __shared__ float colds[64 * 33];   // co[pixel][27]
    __shared__ float wlds[64 * 76];    // per-pixel per-tap {w00,w01,w10,w11,o00c,o01c,o10c,o11c}

    int lane = threadIdx.x & 63;
    int wv = threadIdx.x >> 6;
    int bid = blockIdx.x;
    int logical = (bid & 7) * 256 + (bid >> 3);   // XCD-chunked: bid%8 -> image
    int col = lane & 15;
    int qg = lane >> 4;
    int pl = wv * 16 + col;
    int p = logical * 64 + pl;
    int ow = p & (WW - 1);
    int oh = (p >> 7) & (HH - 1);
    int b = p >> 14;
    const unsigned short* xb = xt + (size_t)b * CC * HH * WW;   // NHWC bf16

    // ---- Phase A: 3x3 conv -> 27 offset/mask channels
    {
        f32x4 acc0 = {0.f,0.f,0.f,0.f}, acc1 = {0.f,0.f,0.f,0.f};
#pragma unroll
        for (int ch = 0; ch < 18; ch++) {
            int k = ch >> 1;
            int c0 = ((ch & 1) << 5) + (qg << 3);
            int iy = oh - 1 + k / 3;
            int ix = ow - 1 + (k - (k / 3) * 3);
            bool vv = (iy >= 0) && (iy < HH) && (ix >= 0) && (ix < WW);
            bf16x8 bfr = {0,0,0,0,0,0,0,0};
            if (vv) bfr = *(const bf16x8*)(xb + (size_t)(iy * WW + ix) * CC + c0);
            bf16x8 a0 = *(const bf16x8*)(w1f + ((size_t)(0 * 18 + ch) * 64 + lane) * 8);
            bf16x8 a1 = *(const bf16x8*)(w1f + ((size_t)(1 * 18 + ch) * 64 + lane) * 8);
            acc0 = __builtin_amdgcn_mfma_f32_16x16x32_bf16(a0, bfr, acc0, 0, 0, 0);
            acc1 = __builtin_amdgcn_mfma_f32_16x16x32_bf16(a1, bfr, acc1, 0, 0, 0);
        }
#pragma unroll
        for (int j = 0; j < 4; j++) {
            int r0 = (qg << 2) + j;
            int r1 = 16 + r0;
            float b1 = (r1 < 18) ? offset_b[r1] : (r1 < 27 ? mask_b[r1 - 18] : 0.f);
            colds[pl * 33 + r0] = acc0[j] + offset_b[r0];
            colds[pl * 33 + r1] = acc1[j] + b1;
        }
    }
    __syncthreads();

    // ---- Hoist, split across qg lanes: taps k with k%4 == qg
    {
        const float* cop = &colds[pl * 33];
        for (int k = qg; k < 9; k += 4) {
            float dy = cop[2 * k];
            float dx = cop[2 * k + 1];
            float mr = cop[18 + k];
            float m = 1.f / (1.f + __expf(-mr));
            float py = (float)(oh - 1 + k / 3) + dy;
            float px = (float)(ow - 1 + (k - (k / 3) * 3)) + dx;
            float y0f = floorf(py), x0f = floorf(px);
            float fy = py - y0f, fx = px - x0f;
            int y0 = (int)y0f, x0 = (int)x0f;
            int y1 = y0 + 1, x1 = x0 + 1;
            bool vy0 = (y0 >= 0) && (y0 < HH), vy1 = (y1 >= 0) && (y1 < HH);
            bool vx0 = (x0 >= 0) && (x0 < WW), vx1 = (x1 >= 0) && (x1 < WW);
            float w00 = (vy0 && vx0) ? (1.f - fy) * (1.f - fx) * m : 0.f;
            float w01 = (vy0 && vx1) ? (1.f - fy) * fx * m : 0.f;
            float w10 = (vy1 && vx0) ? fy * (1.f - fx) * m : 0.f;
            float w11 = (vy1 && vx1) ? fy * fx * m : 0.f;
            int iy0 = min(max(y0, 0), HH - 1), iy1 = min(max(y1, 0), HH - 1);
            int ix0 = min(max(x0, 0), WW - 1), ix1 = min(max(x1, 0), WW - 1);
            float* q = &wlds[pl * 76 + k * 8];
            q[0] = w00; q[1] = w01; q[2] = w10; q[3] = w11;
            q[4] = __builtin_bit_cast(float, (iy0 * WW + ix0) * CC);
            q[5] = __builtin_bit_cast(float, (iy0 * WW + ix1) * CC);
            q[6] = __builtin_bit_cast(float, (iy1 * WW + ix0) * CC);
            q[7] = __builtin_bit_cast(float, (iy1 * WW + ix1) * CC);
        }
    }
    __syncthreads();

    // ---- Phase B: 9 taps, 2-buffer register prefetch pipeline
    f32x4 acc0 = {0.f,0.f,0.f,0.f}, acc1 = {0.f,0.f,0.f,0.f};
    f32x4 acc2 = {0.f,0.f,0.f,0.f}, acc3 = {0.f,0.f,0.f,0.f};

    const unsigned short* xq = xb + (qg << 3);
    const float* wp = &wlds[pl * 76];

    bf16x8 bufA[8], bufB[8];
    f32x4 wA, wB;

    auto LOADK = [&](bf16x8* buf, i32x4 o) {
        buf[0] = *(const bf16x8*)(xq + o[0]);
        buf[1] = *(const bf16x8*)(xq + o[1]);
        buf[2] = *(const bf16x8*)(xq + o[2]);
        buf[3] = *(const bf16x8*)(xq + o[3]);
        buf[4] = *(const bf16x8*)(xq + o[0] + 32);
        buf[5] = *(const bf16x8*)(xq + o[1] + 32);
        buf[6] = *(const bf16x8*)(xq + o[2] + 32);
        buf[7] = *(const bf16x8*)(xq + o[3] + 32);
    };

    auto STEP = [&](bf16x8* cur, bf16x8* nxt, f32x4& wcur, f32x4& wnxt, int k) {
        if (k < 8) {
            wnxt = *(const f32x4*)(wp + (k + 1) * 8);
            i32x4 onx = __builtin_bit_cast(i32x4, *(const f32x4*)(wp + (k + 1) * 8 + 4));
            LOADK(nxt, onx);
        }
#pragma unroll
        for (int h = 0; h < 2; h++) {
            bf16x8 bfr = bilerp8(cur[h*4+0], cur[h*4+1], cur[h*4+2], cur[h*4+3], wcur);
            int ch = 2 * k + h;
            const short* ap = w2f + ((size_t)ch * 64 + lane) * 8;
            bf16x8 a0 = *(const bf16x8*)(ap);
            bf16x8 a1 = *(const bf16x8*)(ap + 18 * 512);
            bf16x8 a2 = *(const bf16x8*)(ap + 36 * 512);
            bf16x8 a3 = *(const bf16x8*)(ap + 54 * 512);
            acc0 = __builtin_amdgcn_mfma_f32_16x16x32_bf16(a0, bfr, acc0, 0, 0, 0);
            acc1 = __builtin_amdgcn_mfma_f32_16x16x32_bf16(a1, bfr, acc1, 0, 0, 0);
            acc2 = __builtin_amdgcn_mfma_f32_16x16x32_bf16(a2, bfr, acc2, 0, 0, 0);
            acc3 = __builtin_amdgcn_mfma_f32_16x16x32_bf16(a3, bfr, acc3, 0, 0, 0);
        }
    };

    {
        wA = *(const f32x4*)(wp);
        i32x4 o0 = __builtin_bit_cast(i32x4, *(const f32x4*)(wp + 4));
        LOADK(bufA, o0);
    }
    STEP(bufA, bufB, wA, wB, 0);
    STEP(bufB, bufA, wB, wA, 1);
    STEP(bufA, bufB, wA, wB, 2);
    STEP(bufB, bufA, wB, wA, 3);
    STEP(bufA, bufB, wA, wB, 4);
    STEP(bufB, bufA, wB, wA, 5);
    STEP(bufA, bufB, wA, wB, 6);
    STEP(bufB, bufA, wB, wA, 7);
    STEP(bufA, bufB, wA, wB, 8);

    size_t ob = (size_t)b * OCC * HH * WW + (size_t)oh * WW + ow;
#pragma unroll
    for (int j = 0; j < 4; j++) {
        int r = (qg << 2) + j;
        out[ob + (size_t)r * HH * WW]        = acc0[j] + bias[r];
        out[ob + (size_t)(r + 16) * HH * WW] = acc1[j] + bias[r + 16];
        out[ob + (size_t)(r + 32) * HH * WW] = acc2[j] + bias[r + 32];
        out[ob + (size_t)(r + 48) * HH * WW] = acc3[j] + bias[r + 48];
    }
}

// ---------------- Fallback (round-1, all-f32, no ws) ----------------
__global__ __launch_bounds__(256)
void deform_fused_fb(const float* __restrict__ x,
                     const float* __restrict__ weight,
                     const float* __restrict__ bias,
                     const float* __restrict__ offset_w,
                     const float* __restrict__ offset_b,
                     const float* __restrict__ mask_w,
                     const float* __restrict__ mask_b,
                     float* __restrict__ out) {
    int p = blockIdx.x * 256 + threadIdx.x;
    int ow = p & (WW - 1);
    int oh = (p >> 7) & (HH - 1);
    int b = p >> 14;
    const float* xb = x + (size_t)b * CC * HH * WW;

    float acc[27];
#pragma unroll
    for (int j = 0; j < 18; j++) acc[j] = offset_b[j];
#pragma unroll
    for (int j = 0; j < 9; j++) acc[18 + j] = mask_b[j];

    for (int c = 0; c < CC; c++) {
        const float* xc = xb + c * HH * WW;
        float xv[9];
#pragma unroll
        for (int t = 0; t < 9; t++) {
            int iy = oh - 1 + t / 3;
            int ix = ow - 1 + t % 3;
            bool v = (iy >= 0) && (iy < HH) && (ix >= 0) && (ix < WW);
            xv[t] = v ? xc[iy * WW + ix] : 0.f;
        }
#pragma unroll
        for (int t = 0; t < 9; t++)
#pragma unroll
            for (int j = 0; j < 27; j++) {
                float wv = (j < 18) ? offset_w[(j * CC + c) * 9 + t]
                                    : mask_w[((j - 18) * CC + c) * 9 + t];
                acc[j] += xv[t] * wv;
            }
    }

    float acc2[OCC];
#pragma unroll
    for (int o = 0; o < OCC; o++) acc2[o] = 0.f;

#pragma unroll
    for (int k = 0; k < 9; k++) {
        float dy = acc[2 * k], dx = acc[2 * k + 1];
        float m = 1.f / (1.f + __expf(-acc[18 + k]));
        float py = (float)(oh - 1 + k / 3) + dy;
        float px = (float)(ow - 1 + k % 3) + dx;
        float y0f = floorf(py), x0f = floorf(px);
        float fy = py - y0f, fx = px - x0f;
        int y0 = (int)y0f, x0 = (int)x0f;
        int y1 = y0 + 1, x1 = x0 + 1;
        bool vy0 = (y0 >= 0) && (y0 < HH), vy1 = (y1 >= 0) && (y1 < HH);
        bool vx0 = (x0 >= 0) && (x0 < WW), vx1 = (x1 >= 0) && (x1 < WW);
        float w00 = (vy0 && vx0) ? (1.f - fy) * (1.f - fx) * m : 0.f;
        float w01 = (vy0 && vx1) ? (1.f - fy) * fx * m : 0.f;
        float w10 = (vy1 && vx0) ? fy * (1.f - fx) * m : 0.f;
        float w11 = (vy1 && vx1) ? fy * fx * m : 0.f;
        int iy0 = min(max(y0, 0), HH - 1), iy1 = min(max(y1, 0), HH - 1);
        int ix0 = min(max(x0, 0), WW - 1), ix1 = min(max(x1, 0), WW - 1);
        int o00 = iy0 * WW + ix0, o01 = iy0 * WW + ix1;
        int o10 = iy1 * WW + ix0, o11 = iy1 * WW + ix1;
        for (int c = 0; c < CC; c++) {
            const float* xc = xb + c * HH * WW;
            float v = w00 * xc[o00] + w01 * xc[o01] + w10 * xc[o10] + w11 * xc[o11];
#pragma unroll
            for (int o = 0; o < OCC; o++) acc2[o] += v * weight[(o * CC + c) * 9 + k];
        }
    }
    float* ob = out + (size_t)b * OCC * HH * WW + oh * WW + ow;
#pragma unroll
    for (int o = 0; o < OCC; o++) ob[(size_t)o * HH * WW] = acc2[o] + bias[o];
}

extern "C" void kernel_launch(void* const* d_in, const int* in_sizes, int n_in,
                              void* d_out, int out_size, void* d_ws, size_t ws_size,
                              hipStream_t stream) {
    const float* x        = (const float*)d_in[0];
    const float* weight   = (const float*)d_in[1];
    const float* bias     = (const float*)d_in[2];
    const float* offset_w = (const float*)d_in[3];
    const float* offset_b = (const float*)d_in[4];
    const float* mask_w   = (const float*)d_in[5];
    const float* mask_b   = (const float*)d_in[6];
    float* out = (float*)d_out;

    if (ws_size >= (size_t)WS_FULL) {
        unsigned short* xt = (unsigned short*)((char*)d_ws + XT_OFF);
        short* w1f = (short*)((char*)d_ws + W1F_OFF);
        short* w2f = (short*)((char*)d_ws + W2F_OFF);
        prep_weights<<<216, 256, 0, stream>>>(weight, offset_w, mask_w, w1f, w2f);
        transpose_x<<<BB * HH, 256, 0, stream>>>(x, xt);
        fused_mfma<<<NPIX / 64, 256, 0, stream>>>(xt, offset_b, mask_b, bias, w1f, w2f, out);
    } else {
        deform_fused_fb<<<NPIX / 256, 256, 0, stream>>>(x, weight, bias, offset_w, offset_b,
                                                        mask_w, mask_b, out);
    }
}

// Round 7
// 85.004 us; speedup vs baseline: 4.4532x; 1.4249x over previous
//
#include <hip/hip_runtime.h>

#define HH 128
#define WW 128
#define CC 64
#define OCC 64
#define BB 8
#define NPIX (BB * HH * WW)   // 131072

typedef __attribute__((ext_vector_type(4))) float f32x4;
typedef __attribute__((ext_vector_type(2))) float f32x2;
typedef __attribute__((ext_vector_type(8))) short bf16x8;
typedef __attribute__((ext_vector_type(4))) unsigned u32x4;

// ---- ws layout (full path) ----
#define XT_OFF 0                         // xt [B][H][W][C] bf16 = 16,777,216 B
#define W1F_OFF 16777216                 // w1f [2][18][64][8] bf16 = 36,864 B
#define W2F_OFF 16814080                 // w2f [4][18][64][8] bf16 = 73,728 B
#define WS_FULL (16814080 + 73728)

// window: 5 rows x 68 cols x 64ch bf16 (swizzled), covers |d| < 1 fast path
#define WROWS 5
#define WCOLS 68
#define WIN_BYTES (WROWS * WCOLS * 128)    // 43520
#define WLDS_FLOATS (64 * 72)              // 18432 B; colds[64*33] overlaid

__device__ __forceinline__ short f2bf(float f) {
    union { float f; unsigned u; } v; v.f = f;
    unsigned r = v.u + 0x7FFF + ((v.u >> 16) & 1);   // RNE
    return (short)(r >> 16);
}

__device__ __forceinline__ unsigned cvtpk_bf16(float lo, float hi) {
    unsigned r;
    asm("v_cvt_pk_bf16_f32 %0, %1, %2" : "=v"(r) : "v"(lo), "v"(hi));
    return r;
}

// Packed bilinear: 8 channels from 4 corner fragments, weights w[0..3].
__device__ __forceinline__ bf16x8 bilerp8(bf16x8 r00, bf16x8 r01, bf16x8 r10, bf16x8 r11,
                                          f32x4 w) {
    u32x4 u00 = __builtin_bit_cast(u32x4, r00);
    u32x4 u01 = __builtin_bit_cast(u32x4, r01);
    u32x4 u10 = __builtin_bit_cast(u32x4, r10);
    u32x4 u11 = __builtin_bit_cast(u32x4, r11);
    u32x4 res;
#pragma unroll
    for (int j = 0; j < 4; j++) {
        f32x2 a, acc;
        a[0] = __builtin_bit_cast(float, (unsigned)(u00[j] << 16));
        a[1] = __builtin_bit_cast(float, (unsigned)(u00[j] & 0xFFFF0000u));
        acc = a * w[0];
        a[0] = __builtin_bit_cast(float, (unsigned)(u01[j] << 16));
        a[1] = __builtin_bit_cast(float, (unsigned)(u01[j] & 0xFFFF0000u));
        acc += a * w[1];
        a[0] = __builtin_bit_cast(float, (unsigned)(u10[j] << 16));
        a[1] = __builtin_bit_cast(float, (unsigned)(u10[j] & 0xFFFF0000u));
        acc += a * w[2];
        a[0] = __builtin_bit_cast(float, (unsigned)(u11[j] << 16));
        a[1] = __builtin_bit_cast(float, (unsigned)(u11[j] & 0xFFFF0000u));
        acc += a * w[3];
        res[j] = cvtpk_bf16(acc[0], acc[1]);
    }
    return __builtin_bit_cast(bf16x8, res);
}

// ---------------- K0: pack weights to MFMA-fragment order ----------------
__global__ void prep_weights(const float* __restrict__ weight,
                             const float* __restrict__ offset_w,
                             const float* __restrict__ mask_w,
                             short* __restrict__ w1f, short* __restrict__ w2f) {
    int tid = blockIdx.x * 256 + threadIdx.x;
    if (tid < 2 * 18 * 64 * 8) {                 // 18432
        int i = tid & 7, lane = (tid >> 3) & 63, ch = (tid >> 9) % 18, tile = tid / (18 * 512);
        int r = tile * 16 + (lane & 15);
        int q = ch * 32 + ((lane >> 4) << 3) + i;
        int k = q >> 6, c = q & 63;
        float v = 0.f;
        if (r < 18)      v = offset_w[(r * CC + c) * 9 + k];
        else if (r < 27) v = mask_w[((r - 18) * CC + c) * 9 + k];
        w1f[tid] = f2bf(v);
    } else {
        int u = tid - 18432;
        if (u < 4 * 18 * 64 * 8) {               // 36864
            int i = u & 7, lane = (u >> 3) & 63, ch = (u >> 9) % 18, tile = u / (18 * 512);
            int oc = tile * 16 + (lane & 15);
            int q = ch * 32 + ((lane >> 4) << 3) + i;
            int k = q >> 6, c = q & 63;
            w2f[u] = f2bf(weight[(oc * CC + c) * 9 + k]);
        }
    }
}

// ---------------- K0b: NCHW f32 -> NHWC bf16 transpose of x ----------------
__global__ __launch_bounds__(256) void transpose_x(
    const float* __restrict__ x, unsigned short* __restrict__ xt) {
    __shared__ float lds[128 * 65];
    int bh = blockIdx.x;           // b*128 + h
    int b = bh >> 7, h = bh & 127;
    const float* xr = x + ((size_t)b * CC * HH + h) * WW;
    int tid = threadIdx.x;
#pragma unroll
    for (int it = 0; it < 32; it++) {
        int e = it * 256 + tid;
        int c = e >> 7, w = e & 127;
        lds[w * 65 + c] = xr[(size_t)c * HH * WW + w];
    }
    __syncthreads();
    unsigned* otr = (unsigned*)(xt + (size_t)bh * WW * CC);   // packed bf16 pairs
#pragma unroll
    for (int it = 0; it < 16; it++) {
        int e = it * 256 + tid;            // pair index: w*32 + cp
        int w = e >> 5, cp = e & 31;
        unsigned lo = (unsigned short)f2bf(lds[w * 65 + 2 * cp]);
        unsigned hi = (unsigned short)f2bf(lds[w * 65 + 2 * cp + 1]);
        otr[e] = lo | (hi << 16);
    }
}

// ---------------- K1: fused conv + deformable einsum, LDS-windowed ----------------
__global__ __launch_bounds__(256) void fused_mfma(
    const unsigned short* __restrict__ xt,
    const float* __restrict__ offset_b,
    const float* __restrict__ mask_b,
    const float* __restrict__ bias,
    const short* __restrict__ w1f,
    const short* __restrict__ w2f,
    float* __restrict__ out) {
    __shared__ char shbuf[WIN_BYTES + WLDS_FLOATS * 4];   // 61952 B
    char* win = shbuf;
    float* wlds = (float*)(shbuf + WIN_BYTES);   // [pl][72]: 9 taps x {4 w, 4 off}
    float* colds = wlds;                         // overlaid [pl][33] (phase A only)

    int lane = threadIdx.x & 63;
    int wv = threadIdx.x >> 6;
    int bid = blockIdx.x;
    int logical = (bid & 7) * 256 + (bid >> 3);   // XCD-chunked: bid%8 -> image
    int col = lane & 15;
    int qg = lane >> 4;
    int pl = wv * 16 + col;
    int p = logical * 64 + pl;
    int ow = p & (WW - 1);
    int oh = (p >> 7) & (HH - 1);
    int b = p >> 14;
    int ow0 = ow & ~63;                           // block-uniform
    const unsigned short* xb = xt + (size_t)b * CC * HH * WW;   // NHWC bf16

    int ylo = max(0, oh - 2), yhi = min(HH - 1, oh + 2);
    int xlo = max(0, ow0 - 2), xhi = min(WW - 1, ow0 + 65);
    int R = yhi - ylo + 1, C = xhi - xlo + 1;

    // ---- Stage window: R x C pixels x 128B, coalesced in, swizzled to LDS
    {
        int C8 = C * 8;
        for (int ry = 0; ry < R; ry++) {
            const unsigned short* src = xb + ((size_t)(ylo + ry) * WW + xlo) * CC;
            for (int t = threadIdx.x; t < C8; t += 256) {
                int rx = t >> 3, s = t & 7;
                u32x4 v = *(const u32x4*)(src + rx * CC + s * 8);
                int pix = ry * WCOLS + rx;
                *(u32x4*)(win + (pix << 7) + ((s ^ (pix & 7)) << 4)) = v;
            }
        }
    }
    __syncthreads();

    // ---- Phase A: 3x3 conv -> 27 offset/mask channels (taps read from window)
    {
        f32x4 acc0 = {0.f,0.f,0.f,0.f}, acc1 = {0.f,0.f,0.f,0.f};
#pragma unroll
        for (int ch = 0; ch < 18; ch++) {
            int k = ch >> 1;
            int iy = oh - 1 + k / 3;
            int ix = ow - 1 + (k - (k / 3) * 3);
            bool vv = (iy >= 0) && (iy < HH) && (ix >= 0) && (ix < WW);
            bf16x8 bfr = {0,0,0,0,0,0,0,0};
            if (vv) {
                int pix = (iy - ylo) * WCOLS + (ix - xlo);
                int s = ((ch & 1) << 2) + qg;
                bfr = *(const bf16x8*)(win + (pix << 7) + ((s ^ (pix & 7)) << 4));
            }
            bf16x8 a0 = *(const bf16x8*)(w1f + ((size_t)(0 * 18 + ch) * 64 + lane) * 8);
            bf16x8 a1 = *(const bf16x8*)(w1f + ((size_t)(1 * 18 + ch) * 64 + lane) * 8);
            acc0 = __builtin_amdgcn_mfma_f32_16x16x32_bf16(a0, bfr, acc0, 0, 0, 0);
            acc1 = __builtin_amdgcn_mfma_f32_16x16x32_bf16(a1, bfr, acc1, 0, 0, 0);
        }
#pragma unroll
        for (int j = 0; j < 4; j++) {
            int r0 = (qg << 2) + j;
            int r1 = 16 + r0;
            float b1 = (r1 < 18) ? offset_b[r1] : (r1 < 27 ? mask_b[r1 - 18] : 0.f);
            colds[pl * 33 + r0] = acc0[j] + offset_b[r0];
            colds[pl * 33 + r1] = acc1[j] + b1;
        }
    }
    __syncthreads();

    // ---- Hoist (qg-split): taps k = qg, qg+4, qg+8; read colds now, store later
    float hw[3][4];
    unsigned ho[3][4];
    {
        const float* cop = &colds[pl * 33];
#pragma unroll
        for (int ki = 0; ki < 3; ki++) {
            int k = qg + ki * 4;
            if (k < 9) {
                float dy = cop[2 * k];
                float dx = cop[2 * k + 1];
                float mr = cop[18 + k];
                float m = 1.f / (1.f + __expf(-mr));
                float py = (float)(oh - 1 + k / 3) + dy;
                float px = (float)(ow - 1 + (k - (k / 3) * 3)) + dx;
                float y0f = floorf(py), x0f = floorf(px);
                float fy = py - y0f, fx = px - x0f;
                int y0 = (int)y0f, x0 = (int)x0f;
                int y1 = y0 + 1, x1 = x0 + 1;
                bool vy0 = (y0 >= 0) && (y0 < HH), vy1 = (y1 >= 0) && (y1 < HH);
                bool vx0 = (x0 >= 0) && (x0 < WW), vx1 = (x1 >= 0) && (x1 < WW);
                hw[ki][0] = (vy0 && vx0) ? (1.f - fy) * (1.f - fx) * m : 0.f;
                hw[ki][1] = (vy0 && vx1) ? (1.f - fy) * fx * m : 0.f;
                hw[ki][2] = (vy1 && vx0) ? fy * (1.f - fx) * m : 0.f;
                hw[ki][3] = (vy1 && vx1) ? fy * fx * m : 0.f;
                int iy0 = min(max(y0, 0), HH - 1), iy1 = min(max(y1, 0), HH - 1);
                int ix0 = min(max(x0, 0), WW - 1), ix1 = min(max(x1, 0), WW - 1);
                int wy0 = iy0 - ylo, wy1 = iy1 - ylo;
                int wx0 = ix0 - xlo, wx1 = ix1 - xlo;
                bool fast = (wy0 >= 0) && (wy1 < R) && (wx0 >= 0) && (wx1 < C);
                if (fast) {
                    ho[ki][0] = (unsigned)((wy0 * WCOLS + wx0) << 7);
                    ho[ki][1] = (unsigned)((wy0 * WCOLS + wx1) << 7);
                    ho[ki][2] = (unsigned)((wy1 * WCOLS + wx0) << 7);
                    ho[ki][3] = (unsigned)((wy1 * WCOLS + wx1) << 7);
                } else {
                    ho[ki][0] = (unsigned)((iy0 * WW + ix0) * CC) | 0x80000000u;
                    ho[ki][1] = (unsigned)((iy0 * WW + ix1) * CC) | 0x80000000u;
                    ho[ki][2] = (unsigned)((iy1 * WW + ix0) * CC) | 0x80000000u;
                    ho[ki][3] = (unsigned)((iy1 * WW + ix1) * CC) | 0x80000000u;
                }
            }
        }
    }
    __syncthreads();   // all colds reads done; safe to overwrite with wlds
#pragma unroll
    for (int ki = 0; ki < 3; ki++) {
        int k = qg + ki * 4;
        if (k < 9) {
            float* q = &wlds[pl * 72 + k * 8];
            q[0] = hw[ki][0]; q[1] = hw[ki][1]; q[2] = hw[ki][2]; q[3] = hw[ki][3];
            ((unsigned*)q)[4] = ho[ki][0]; ((unsigned*)q)[5] = ho[ki][1];
            ((unsigned*)q)[6] = ho[ki][2]; ((unsigned*)q)[7] = ho[ki][3];
        }
    }
    __syncthreads();

    // ---- Phase B: 9 taps, corners from LDS window (rare global slow path)
    f32x4 acc0 = {0.f,0.f,0.f,0.f}, acc1 = {0.f,0.f,0.f,0.f};
    f32x4 acc2 = {0.f,0.f,0.f,0.f}, acc3 = {0.f,0.f,0.f,0.f};
    const float* wp = &wlds[pl * 72];
    const unsigned short* xq = xb + (qg << 3);
    unsigned sh0 = (unsigned)(qg << 4);
    unsigned sh1 = sh0 + 64;

#pragma unroll
    for (int k = 0; k < 9; k++) {
        f32x4 wq = *(const f32x4*)(wp + k * 8);
        u32x4 o = __builtin_bit_cast(u32x4, *(const f32x4*)(wp + k * 8 + 4));
        bf16x8 h0[4], h1[4];
        if (!(o[0] & 0x80000000u)) {
#pragma unroll
            for (int c = 0; c < 4; c++) {
                unsigned base = o[c];
                unsigned swz = (base >> 3) & 0x70;
                h0[c] = *(const bf16x8*)(win + base + (sh0 ^ swz));
                h1[c] = *(const bf16x8*)(win + base + (sh1 ^ swz));
            }
        } else {
#pragma unroll
            for (int c = 0; c < 4; c++) {
                unsigned off = o[c] & 0x7FFFFFFFu;
                h0[c] = *(const bf16x8*)(xq + off);
                h1[c] = *(const bf16x8*)(xq + off + 32);
            }
        }
        bf16x8 bf0 = bilerp8(h0[0], h0[1], h0[2], h0[3], wq);
        bf16x8 bf1 = bilerp8(h1[0], h1[1], h1[2], h1[3], wq);
#pragma unroll
        for (int h = 0; h < 2; h++) {
            bf16x8 bfr = h ? bf1 : bf0;
            int ch = 2 * k + h;
            const short* ap = w2f + ((size_t)ch * 64 + lane) * 8;
            bf16x8 a0 = *(const bf16x8*)(ap);
            bf16x8 a1 = *(const bf16x8*)(ap + 18 * 512);
            bf16x8 a2 = *(const bf16x8*)(ap + 36 * 512);
            bf16x8 a3 = *(const bf16x8*)(ap + 54 * 512);
            acc0 = __builtin_amdgcn_mfma_f32_16x16x32_bf16(a0, bfr, acc0, 0, 0, 0);
            acc1 = __builtin_amdgcn_mfma_f32_16x16x32_bf16(a1, bfr, acc1, 0, 0, 0);
            acc2 = __builtin_amdgcn_mfma_f32_16x16x32_bf16(a2, bfr, acc2, 0, 0, 0);
            acc3 = __builtin_amdgcn_mfma_f32_16x16x32_bf16(a3, bfr, acc3, 0, 0, 0);
        }
    }

    size_t ob = (size_t)b * OCC * HH * WW + (size_t)oh * WW + ow;
#pragma unroll
    for (int j = 0; j < 4; j++) {
        int r = (qg << 2) + j;
        out[ob + (size_t)r * HH * WW]        = acc0[j] + bias[r];
        out[ob + (size_t)(r + 16) * HH * WW] = acc1[j] + bias[r + 16];
        out[ob + (size_t)(r + 32) * HH * WW] = acc2[j] + bias[r + 32];
        out[ob + (size_t)(r + 48) * HH * WW] = acc3[j] + bias[r + 48];
    }
}

// ---------------- Fallback (round-1, all-f32, no ws) ----------------
__global__ __launch_bounds__(256)
void deform_fused_fb(const float* __restrict__ x,
                     const float* __restrict__ weight,
                     const float* __restrict__ bias,
                     const float* __restrict__ offset_w,
                     const float* __restrict__ offset_b,
                     const float* __restrict__ mask_w,
                     const float* __restrict__ mask_b,
                     float* __restrict__ out) {
    int p = blockIdx.x * 256 + threadIdx.x;
    int ow = p & (WW - 1);
    int oh = (p >> 7) & (HH - 1);
    int b = p >> 14;
    const float* xb = x + (size_t)b * CC * HH * WW;

    float acc[27];
#pragma unroll
    for (int j = 0; j < 18; j++) acc[j] = offset_b[j];
#pragma unroll
    for (int j = 0; j < 9; j++) acc[18 + j] = mask_b[j];

    for (int c = 0; c < CC; c++) {
        const float* xc = xb + c * HH * WW;
        float xv[9];
#pragma unroll
        for (int t = 0; t < 9; t++) {
            int iy = oh - 1 + t / 3;
            int ix = ow - 1 + t % 3;
            bool v = (iy >= 0) && (iy < HH) && (ix >= 0) && (ix < WW);
            xv[t] = v ? xc[iy * WW + ix] : 0.f;
        }
#pragma unroll
        for (int t = 0; t < 9; t++)
#pragma unroll
            for (int j = 0; j < 27; j++) {
                float wv = (j < 18) ? offset_w[(j * CC + c) * 9 + t]
                                    : mask_w[((j - 18) * CC + c) * 9 + t];
                acc[j] += xv[t] * wv;
            }
    }

    float acc2[OCC];
#pragma unroll
    for (int o = 0; o < OCC; o++) acc2[o] = 0.f;

#pragma unroll
    for (int k = 0; k < 9; k++) {
        float dy = acc[2 * k], dx = acc[2 * k + 1];
        float m = 1.f / (1.f + __expf(-acc[18 + k]));
        float py = (float)(oh - 1 + k / 3) + dy;
        float px = (float)(ow - 1 + k % 3) + dx;
        float y0f = floorf(py), x0f = floorf(px);
        float fy = py - y0f, fx = px - x0f;
        int y0 = (int)y0f, x0 = (int)x0f;
        int y1 = y0 + 1, x1 = x0 + 1;
        bool vy0 = (y0 >= 0) && (y0 < HH), vy1 = (y1 >= 0) && (y1 < HH);
        bool vx0 = (x0 >= 0) && (x0 < WW), vx1 = (x1 >= 0) && (x1 < WW);
        float w00 = (vy0 && vx0) ? (1.f - fy) * (1.f - fx) * m : 0.f;
        float w01 = (vy0 && vx1) ? (1.f - fy) * fx * m : 0.f;
        float w10 = (vy1 && vx0) ? fy * (1.f - fx) * m : 0.f;
        float w11 = (vy1 && vx1) ? fy * fx * m : 0.f;
        int iy0 = min(max(y0, 0), HH - 1), iy1 = min(max(y1, 0), HH - 1);
        int ix0 = min(max(x0, 0), WW - 1), ix1 = min(max(x1, 0), WW - 1);
        int o00 = iy0 * WW + ix0, o01 = iy0 * WW + ix1;
        int o10 = iy1 * WW + ix0, o11 = iy1 * WW + ix1;
        for (int c = 0; c < CC; c++) {
            const float* xc = xb + c * HH * WW;
            float v = w00 * xc[o00] + w01 * xc[o01] + w10 * xc[o10] + w11 * xc[o11];
#pragma unroll
            for (int o = 0; o < OCC; o++) acc2[o] += v * weight[(o * CC + c) * 9 + k];
        }
    }
    float* ob = out + (size_t)b * OCC * HH * WW + oh * WW + ow;
#pragma unroll
    for (int o = 0; o < OCC; o++) ob[(size_t)o * HH * WW] = acc2[o] + bias[o];
}

extern "C" void kernel_launch(void* const* d_in, const int* in_sizes, int n_in,
                              void* d_out, int out_size, void* d_ws, size_t ws_size,
                              hipStream_t stream) {
    const float* x        = (const float*)d_in[0];
    const float* weight   = (const float*)d_in[1];
    const float* bias     = (const float*)d_in[2];
    const float* offset_w = (const float*)d_in[3];
    const float* offset_b = (const float*)d_in[4];
    const float* mask_w   = (const float*)d_in[5];
    const float* mask_b   = (const float*)d_in[6];
    float* out = (float*)d_out;

    if (ws_size >= (size_t)WS_FULL) {
        unsigned short* xt = (unsigned short*)((char*)d_ws + XT_OFF);
        short* w1f = (short*)((char*)d_ws + W1F_OFF);
        short* w2f = (short*)((char*)d_ws + W2F_OFF);
        prep_weights<<<216, 256, 0, stream>>>(weight, offset_w, mask_w, w1f, w2f);
        transpose_x<<<BB * HH, 256, 0, stream>>>(x, xt);
        fused_mfma<<<NPIX / 64, 256, 0, stream>>>(xt, offset_b, mask_b, bias, w1f, w2f, out);
    } else {
        deform_fused_fb<<<NPIX / 256, 256, 0, stream>>>(x, weight, bias, offset_w, offset_b,
                                                        mask_w, mask_b, out);
    }
}

// Round 10
// 76.713 us; speedup vs baseline: 4.9346x; 1.1081x over previous
//
#include <hip/hip_runtime.h>

#define HH 128
#define WW 128
#define CC 64
#define OCC 64
#define BB 8
#define NPIX (BB * HH * WW)   // 131072

typedef __attribute__((ext_vector_type(4))) float f32x4;
typedef __attribute__((ext_vector_type(2))) float f32x2;
typedef __attribute__((ext_vector_type(8))) short bf16x8;
typedef __attribute__((ext_vector_type(4))) unsigned u32x4;

// ---- ws layout (full path) ----
#define XT_OFF 0                         // xt [B][H][W][C] bf16 = 16,777,216 B
#define W1F_OFF 16777216                 // w1f [2][18][64][8] bf16 = 36,864 B
#define W2F_OFF 16814080                 // w2f [4][18][64][8] bf16 = 73,728 B
#define WS_FULL (16814080 + 73728)

// window: 4 rows (oh-1..oh+2) x 68 cols x 64ch bf16 (swizzled).
// Phase A taps (rows oh-1..oh+1) always covered; Phase B corners at y0=oh-2
// (~1/6 of taps) take the verified global slow path.
#define WROWS 4
#define WCOLS 68
#define WIN_BYTES (WROWS * WCOLS * 128)    // 34816
#define WLDS_FLOATS (64 * 72)              // 18432 B; colds[64*33] overlaid
// shbuf total = 34816 + 73728/4... = 34816 + 18432*4? no: 34816 + 73728 B? see below

__device__ __forceinline__ short f2bf(float f) {
    union { float f; unsigned u; } v; v.f = f;
    unsigned r = v.u + 0x7FFF + ((v.u >> 16) & 1);   // RNE
    return (short)(r >> 16);
}

__device__ __forceinline__ unsigned cvtpk_bf16(float lo, float hi) {
    unsigned r;
    asm("v_cvt_pk_bf16_f32 %0, %1, %2" : "=v"(r) : "v"(lo), "v"(hi));
    return r;
}

// Packed bilinear: 8 channels from 4 corner fragments, weights w[0..3].
__device__ __forceinline__ bf16x8 bilerp8(bf16x8 r00, bf16x8 r01, bf16x8 r10, bf16x8 r11,
                                          f32x4 w) {
    u32x4 u00 = __builtin_bit_cast(u32x4, r00);
    u32x4 u01 = __builtin_bit_cast(u32x4, r01);
    u32x4 u10 = __builtin_bit_cast(u32x4, r10);
    u32x4 u11 = __builtin_bit_cast(u32x4, r11);
    u32x4 res;
#pragma unroll
    for (int j = 0; j < 4; j++) {
        f32x2 a, acc;
        a[0] = __builtin_bit_cast(float, (unsigned)(u00[j] << 16));
        a[1] = __builtin_bit_cast(float, (unsigned)(u00[j] & 0xFFFF0000u));
        acc = a * w[0];
        a[0] = __builtin_bit_cast(float, (unsigned)(u01[j] << 16));
        a[1] = __builtin_bit_cast(float, (unsigned)(u01[j] & 0xFFFF0000u));
        acc += a * w[1];
        a[0] = __builtin_bit_cast(float, (unsigned)(u10[j] << 16));
        a[1] = __builtin_bit_cast(float, (unsigned)(u10[j] & 0xFFFF0000u));
        acc += a * w[2];
        a[0] = __builtin_bit_cast(float, (unsigned)(u11[j] << 16));
        a[1] = __builtin_bit_cast(float, (unsigned)(u11[j] & 0xFFFF0000u));
        acc += a * w[3];
        res[j] = cvtpk_bf16(acc[0], acc[1]);
    }
    return __builtin_bit_cast(bf16x8, res);
}

// ---------------- K0: pack weights to MFMA-fragment order ----------------
__global__ void prep_weights(const float* __restrict__ weight,
                             const float* __restrict__ offset_w,
                             const float* __restrict__ mask_w,
                             short* __restrict__ w1f, short* __restrict__ w2f) {
    int tid = blockIdx.x * 256 + threadIdx.x;
    if (tid < 2 * 18 * 64 * 8) {                 // 18432
        int i = tid & 7, lane = (tid >> 3) & 63, ch = (tid >> 9) % 18, tile = tid / (18 * 512);
        int r = tile * 16 + (lane & 15);
        int q = ch * 32 + ((lane >> 4) << 3) + i;
        int k = q >> 6, c = q & 63;
        float v = 0.f;
        if (r < 18)      v = offset_w[(r * CC + c) * 9 + k];
        else if (r < 27) v = mask_w[((r - 18) * CC + c) * 9 + k];
        w1f[tid] = f2bf(v);
    } else {
        int u = tid - 18432;
        if (u < 4 * 18 * 64 * 8) {               // 36864
            int i = u & 7, lane = (u >> 3) & 63, ch = (u >> 9) % 18, tile = u / (18 * 512);
            int oc = tile * 16 + (lane & 15);
            int q = ch * 32 + ((lane >> 4) << 3) + i;
            int k = q >> 6, c = q & 63;
            w2f[u] = f2bf(weight[(oc * CC + c) * 9 + k]);
        }
    }
}

// ---------------- K0b: NCHW f32 -> NHWC bf16 transpose of x ----------------
__global__ __launch_bounds__(256) void transpose_x(
    const float* __restrict__ x, unsigned short* __restrict__ xt) {
    __shared__ float lds[128 * 65];
    int bh = blockIdx.x;           // b*128 + h
    int b = bh >> 7, h = bh & 127;
    const float* xr = x + ((size_t)b * CC * HH + h) * WW;
    int tid = threadIdx.x;
#pragma unroll
    for (int it = 0; it < 32; it++) {
        int e = it * 256 + tid;
        int c = e >> 7, w = e & 127;
        lds[w * 65 + c] = xr[(size_t)c * HH * WW + w];
    }
    __syncthreads();
    unsigned* otr = (unsigned*)(xt + (size_t)bh * WW * CC);   // packed bf16 pairs
#pragma unroll
    for (int it = 0; it < 16; it++) {
        int e = it * 256 + tid;            // pair index: w*32 + cp
        int w = e >> 5, cp = e & 31;
        unsigned lo = (unsigned short)f2bf(lds[w * 65 + 2 * cp]);
        unsigned hi = (unsigned short)f2bf(lds[w * 65 + 2 * cp + 1]);
        otr[e] = lo | (hi << 16);
    }
}

// ---------------- K1: fused conv + deformable einsum, LDS-windowed ----------------
__global__ __launch_bounds__(256) void fused_mfma(
    const unsigned short* __restrict__ xt,
    const float* __restrict__ offset_b,
    const float* __restrict__ mask_b,
    const float* __restrict__ bias,
    const short* __restrict__ w1f,
    const short* __restrict__ w2f,
    float* __restrict__ out) {
    __shared__ char shbuf[WIN_BYTES + WLDS_FLOATS * 4];   // 34816 + 18432 = 53248 B
    char* win = shbuf;
    float* wlds = (float*)(shbuf + WIN_BYTES);   // [pl][72]: 9 taps x {4 w, 4 off}
    float* colds = wlds;                         // overlaid [pl][33] (phase A only)

    int lane = threadIdx.x & 63;
    int wv = threadIdx.x >> 6;
    int bid = blockIdx.x;
    int logical = (bid & 7) * 256 + (bid >> 3);   // XCD-chunked: bid%8 -> image
    int col = lane & 15;
    int qg = lane >> 4;
    int pl = wv * 16 + col;
    int p = logical * 64 + pl;
    int ow = p & (WW - 1);
    int oh = (p >> 7) & (HH - 1);
    int b = p >> 14;
    int ow0 = ow & ~63;                           // block-uniform
    const unsigned short* xb = xt + (size_t)b * CC * HH * WW;   // NHWC bf16

    int ylo = max(0, oh - 1), yhi = min(HH - 1, oh + 2);
    int xlo = max(0, ow0 - 2), xhi = min(WW - 1, ow0 + 65);
    int R = yhi - ylo + 1, C = xhi - xlo + 1;

    // ---- Stage window: R x C pixels x 128B, coalesced in, swizzled to LDS
    {
        int C8 = C * 8;
        for (int ry = 0; ry < R; ry++) {
            const unsigned short* src = xb + ((size_t)(ylo + ry) * WW + xlo) * CC;
            for (int t = threadIdx.x; t < C8; t += 256) {
                int rx = t >> 3, s = t & 7;
                u32x4 v = *(const u32x4*)(src + rx * CC + s * 8);
                int pix = ry * WCOLS + rx;
                *(u32x4*)(win + (pix << 7) + ((s ^ (pix & 7)) << 4)) = v;
            }
        }
    }
    __syncthreads();

    // ---- Phase A: 3x3 conv -> 27 offset/mask channels (taps read from window)
    {
        f32x4 acc0 = {0.f,0.f,0.f,0.f}, acc1 = {0.f,0.f,0.f,0.f};
#pragma unroll
        for (int ch = 0; ch < 18; ch++) {
            int k = ch >> 1;
            int iy = oh - 1 + k / 3;
            int ix = ow - 1 + (k - (k / 3) * 3);
            bool vv = (iy >= 0) && (iy < HH) && (ix >= 0) && (ix < WW);
            bf16x8 bfr = {0,0,0,0,0,0,0,0};
            if (vv) {
                int pix = (iy - ylo) * WCOLS + (ix - xlo);
                int s = ((ch & 1) << 2) + qg;
                bfr = *(const bf16x8*)(win + (pix << 7) + ((s ^ (pix & 7)) << 4));
            }
            bf16x8 a0 = *(const bf16x8*)(w1f + ((size_t)(0 * 18 + ch) * 64 + lane) * 8);
            bf16x8 a1 = *(const bf16x8*)(w1f + ((size_t)(1 * 18 + ch) * 64 + lane) * 8);
            acc0 = __builtin_amdgcn_mfma_f32_16x16x32_bf16(a0, bfr, acc0, 0, 0, 0);
            acc1 = __builtin_amdgcn_mfma_f32_16x16x32_bf16(a1, bfr, acc1, 0, 0, 0);
        }
#pragma unroll
        for (int j = 0; j < 4; j++) {
            int r0 = (qg << 2) + j;
            int r1 = 16 + r0;
            float b1 = (r1 < 18) ? offset_b[r1] : (r1 < 27 ? mask_b[r1 - 18] : 0.f);
            colds[pl * 33 + r0] = acc0[j] + offset_b[r0];
            colds[pl * 33 + r1] = acc1[j] + b1;
        }
    }
    __syncthreads();

    // ---- Hoist (qg-split): taps k = qg, qg+4, qg+8; read colds now, store later
    float hw[3][4];
    unsigned ho[3][4];
    {
        const float* cop = &colds[pl * 33];
#pragma unroll
        for (int ki = 0; ki < 3; ki++) {
            int k = qg + ki * 4;
            if (k < 9) {
                float dy = cop[2 * k];
                float dx = cop[2 * k + 1];
                float mr = cop[18 + k];
                float m = 1.f / (1.f + __expf(-mr));
                float py = (float)(oh - 1 + k / 3) + dy;
                float px = (float)(ow - 1 + (k - (k / 3) * 3)) + dx;
                float y0f = floorf(py), x0f = floorf(px);
                float fy = py - y0f, fx = px - x0f;
                int y0 = (int)y0f, x0 = (int)x0f;
                int y1 = y0 + 1, x1 = x0 + 1;
                bool vy0 = (y0 >= 0) && (y0 < HH), vy1 = (y1 >= 0) && (y1 < HH);
                bool vx0 = (x0 >= 0) && (x0 < WW), vx1 = (x1 >= 0) && (x1 < WW);
                hw[ki][0] = (vy0 && vx0) ? (1.f - fy) * (1.f - fx) * m : 0.f;
                hw[ki][1] = (vy0 && vx1) ? (1.f - fy) * fx * m : 0.f;
                hw[ki][2] = (vy1 && vx0) ? fy * (1.f - fx) * m : 0.f;
                hw[ki][3] = (vy1 && vx1) ? fy * fx * m : 0.f;
                int iy0 = min(max(y0, 0), HH - 1), iy1 = min(max(y1, 0), HH - 1);
                int ix0 = min(max(x0, 0), WW - 1), ix1 = min(max(x1, 0), WW - 1);
                int wy0 = iy0 - ylo, wy1 = iy1 - ylo;
                int wx0 = ix0 - xlo, wx1 = ix1 - xlo;
                bool fast = (wy0 >= 0) && (wy1 < R) && (wx0 >= 0) && (wx1 < C);
                if (fast) {
                    ho[ki][0] = (unsigned)((wy0 * WCOLS + wx0) << 7);
                    ho[ki][1] = (unsigned)((wy0 * WCOLS + wx1) << 7);
                    ho[ki][2] = (unsigned)((wy1 * WCOLS + wx0) << 7);
                    ho[ki][3] = (unsigned)((wy1 * WCOLS + wx1) << 7);
                } else {
                    ho[ki][0] = (unsigned)((iy0 * WW + ix0) * CC) | 0x80000000u;
                    ho[ki][1] = (unsigned)((iy0 * WW + ix1) * CC) | 0x80000000u;
                    ho[ki][2] = (unsigned)((iy1 * WW + ix0) * CC) | 0x80000000u;
                    ho[ki][3] = (unsigned)((iy1 * WW + ix1) * CC) | 0x80000000u;
                }
            }
        }
    }
    __syncthreads();   // all colds reads done; safe to overwrite with wlds
#pragma unroll
    for (int ki = 0; ki < 3; ki++) {
        int k = qg + ki * 4;
        if (k < 9) {
            float* q = &wlds[pl * 72 + k * 8];
            q[0] = hw[ki][0]; q[1] = hw[ki][1]; q[2] = hw[ki][2]; q[3] = hw[ki][3];
            ((unsigned*)q)[4] = ho[ki][0]; ((unsigned*)q)[5] = ho[ki][1];
            ((unsigned*)q)[6] = ho[ki][2]; ((unsigned*)q)[7] = ho[ki][3];
        }
    }
    __syncthreads();

    // ---- Phase B: 9 taps, corners from LDS window (y0=oh-2 etc. -> global slow path)
    f32x4 acc0 = {0.f,0.f,0.f,0.f}, acc1 = {0.f,0.f,0.f,0.f};
    f32x4 acc2 = {0.f,0.f,0.f,0.f}, acc3 = {0.f,0.f,0.f,0.f};
    const float* wp = &wlds[pl * 72];
    const unsigned short* xq = xb + (qg << 3);
    unsigned sh0 = (unsigned)(qg << 4);
    unsigned sh1 = sh0 + 64;

#pragma unroll
    for (int k = 0; k < 9; k++) {
        f32x4 wq = *(const f32x4*)(wp + k * 8);
        u32x4 o = __builtin_bit_cast(u32x4, *(const f32x4*)(wp + k * 8 + 4));
        bf16x8 h0[4], h1[4];
        if (!(o[0] & 0x80000000u)) {
#pragma unroll
            for (int c = 0; c < 4; c++) {
                unsigned base = o[c];
                unsigned swz = (base >> 3) & 0x70;
                h0[c] = *(const bf16x8*)(win + base + (sh0 ^ swz));
                h1[c] = *(const bf16x8*)(win + base + (sh1 ^ swz));
            }
        } else {
#pragma unroll
            for (int c = 0; c < 4; c++) {
                unsigned off = o[c] & 0x7FFFFFFFu;
                h0[c] = *(const bf16x8*)(xq + off);
                h1[c] = *(const bf16x8*)(xq + off + 32);
            }
        }
        bf16x8 bf0 = bilerp8(h0[0], h0[1], h0[2], h0[3], wq);
        bf16x8 bf1 = bilerp8(h1[0], h1[1], h1[2], h1[3], wq);
#pragma unroll
        for (int h = 0; h < 2; h++) {
            bf16x8 bfr = h ? bf1 : bf0;
            int ch = 2 * k + h;
            const short* ap = w2f + ((size_t)ch * 64 + lane) * 8;
            bf16x8 a0 = *(const bf16x8*)(ap);
            bf16x8 a1 = *(const bf16x8*)(ap + 18 * 512);
            bf16x8 a2 = *(const bf16x8*)(ap + 36 * 512);
            bf16x8 a3 = *(const bf16x8*)(ap + 54 * 512);
            acc0 = __builtin_amdgcn_mfma_f32_16x16x32_bf16(a0, bfr, acc0, 0, 0, 0);
            acc1 = __builtin_amdgcn_mfma_f32_16x16x32_bf16(a1, bfr, acc1, 0, 0, 0);
            acc2 = __builtin_amdgcn_mfma_f32_16x16x32_bf16(a2, bfr, acc2, 0, 0, 0);
            acc3 = __builtin_amdgcn_mfma_f32_16x16x32_bf16(a3, bfr, acc3, 0, 0, 0);
        }
    }

    size_t ob = (size_t)b * OCC * HH * WW + (size_t)oh * WW + ow;
#pragma unroll
    for (int j = 0; j < 4; j++) {
        int r = (qg << 2) + j;
        out[ob + (size_t)r * HH * WW]        = acc0[j] + bias[r];
        out[ob + (size_t)(r + 16) * HH * WW] = acc1[j] + bias[r + 16];
        out[ob + (size_t)(r + 32) * HH * WW] = acc2[j] + bias[r + 32];
        out[ob + (size_t)(r + 48) * HH * WW] = acc3[j] + bias[r + 48];
    }
}

// ---------------- Fallback (round-1, all-f32, no ws) ----------------
__global__ __launch_bounds__(256)
void deform_fused_fb(const float* __restrict__ x,
                     const float* __restrict__ weight,
                     const float* __restrict__ bias,
                     const float* __restrict__ offset_w,
                     const float* __restrict__ offset_b,
                     const float* __restrict__ mask_w,
                     const float* __restrict__ mask_b,
                     float* __restrict__ out) {
    int p = blockIdx.x * 256 + threadIdx.x;
    int ow = p & (WW - 1);
    int oh = (p >> 7) & (HH - 1);
    int b = p >> 14;
    const float* xb = x + (size_t)b * CC * HH * WW;

    float acc[27];
#pragma unroll
    for (int j = 0; j < 18; j++) acc[j] = offset_b[j];
#pragma unroll
    for (int j = 0; j < 9; j++) acc[18 + j] = mask_b[j];

    for (int c = 0; c < CC; c++) {
        const float* xc = xb + c * HH * WW;
        float xv[9];
#pragma unroll
        for (int t = 0; t < 9; t++) {
            int iy = oh - 1 + t / 3;
            int ix = ow - 1 + t % 3;
            bool v = (iy >= 0) && (iy < HH) && (ix >= 0) && (ix < WW);
            xv[t] = v ? xc[iy * WW + ix] : 0.f;
        }
#pragma unroll
        for (int t = 0; t < 9; t++)
#pragma unroll
            for (int j = 0; j < 27; j++) {
                float wv = (j < 18) ? offset_w[(j * CC + c) * 9 + t]
                                    : mask_w[((j - 18) * CC + c) * 9 + t];
                acc[j] += xv[t] * wv;
            }
    }

    float acc2[OCC];
#pragma unroll
    for (int o = 0; o < OCC; o++) acc2[o] = 0.f;

#pragma unroll
    for (int k = 0; k < 9; k++) {
        float dy = acc[2 * k], dx = acc[2 * k + 1];
        float m = 1.f / (1.f + __expf(-acc[18 + k]));
        float py = (float)(oh - 1 + k / 3) + dy;
        float px = (float)(ow - 1 + k % 3) + dx;
        float y0f = floorf(py), x0f = floorf(px);
        float fy = py - y0f, fx = px - x0f;
        int y0 = (int)y0f, x0 = (int)x0f;
        int y1 = y0 + 1, x1 = x0 + 1;
        bool vy0 = (y0 >= 0) && (y0 < HH), vy1 = (y1 >= 0) && (y1 < HH);
        bool vx0 = (x0 >= 0) && (x0 < WW), vx1 = (x1 >= 0) && (x1 < WW);
        float w00 = (vy0 && vx0) ? (1.f - fy) * (1.f - fx) * m : 0.f;
        float w01 = (vy0 && vx1) ? (1.f - fy) * fx * m : 0.f;
        float w10 = (vy1 && vx0) ? fy * (1.f - fx) * m : 0.f;
        float w11 = (vy1 && vx1) ? fy * fx * m : 0.f;
        int iy0 = min(max(y0, 0), HH - 1), iy1 = min(max(y1, 0), HH - 1);
        int ix0 = min(max(x0, 0), WW - 1), ix1 = min(max(x1, 0), WW - 1);
        int o00 = iy0 * WW + ix0, o01 = iy0 * WW + ix1;
        int o10 = iy1 * WW + ix0, o11 = iy1 * WW + ix1;
        for (int c = 0; c < CC; c++) {
            const float* xc = xb + c * HH * WW;
            float v = w00 * xc[o00] + w01 * xc[o01] + w10 * xc[o10] + w11 * xc[o11];
#pragma unroll
            for (int o = 0; o < OCC; o++) acc2[o] += v * weight[(o * CC + c) * 9 + k];
        }
    }
    float* ob = out + (size_t)b * OCC * HH * WW + oh * WW + ow;
#pragma unroll
    for (int o = 0; o < OCC; o++) ob[(size_t)o * HH * WW] = acc2[o] + bias[o];
}

extern "C" void kernel_launch(void* const* d_in, const int* in_sizes, int n_in,
                              void* d_out, int out_size, void* d_ws, size_t ws_size,
                              hipStream_t stream) {
    const float* x        = (const float*)d_in[0];
    const float* weight   = (const float*)d_in[1];
    const float* bias     = (const float*)d_in[2];
    const float* offset_w = (const float*)d_in[3];
    const float* offset_b = (const float*)d_in[4];
    const float* mask_w   = (const float*)d_in[5];
    const float* mask_b   = (const float*)d_in[6];
    float* out = (float*)d_out;

    if (ws_size >= (size_t)WS_FULL) {
        unsigned short* xt = (unsigned short*)((char*)d_ws + XT_OFF);
        short* w1f = (short*)((char*)d_ws + W1F_OFF);
        short* w2f = (short*)((char*)d_ws + W2F_OFF);
        prep_weights<<<216, 256, 0, stream>>>(weight, offset_w, mask_w, w1f, w2f);
        transpose_x<<<BB * HH, 256, 0, stream>>>(x, xt);
        fused_mfma<<<NPIX / 64, 256, 0, stream>>>(xt, offset_b, mask_b, bias, w1f, w2f, out);
    } else {
        deform_fused_fb<<<NPIX / 256, 256, 0, stream>>>(x, weight, bias, offset_w, offset_b,
                                                        mask_w, mask_b, out);
    }
}